// Round 5
// baseline (1304.366 us; speedup 1.0000x reference)
//
#include <hip/hip_runtime.h>

#define N_NODES 50000
#define N_EDGES 800000

typedef __attribute__((ext_vector_type(8))) short bf16x8;
typedef __attribute__((ext_vector_type(4))) float f32x4;
typedef __attribute__((ext_vector_type(2))) float f32x2;

__device__ __forceinline__ float bf2f(unsigned int u) {
  union { unsigned int u; float f; } c; c.u = (u & 0xffffu) << 16; return c.f;
}
// round-half-up: same half-ulp bound as RNE (differs only on exact ties)
__device__ __forceinline__ unsigned short f2bf(float f) {
  union { float f; unsigned int u; } c; c.f = f;
  return (unsigned short)((c.u + 0x8000u) >> 16);
}
__device__ __forceinline__ float sspf(float x) {
  return fmaxf(x, 0.0f) + __logf(1.0f + __expf(-fabsf(x))) - 0.69314718055994531f;
}
__device__ __forceinline__ f32x4 MFMA(bf16x8 a, bf16x8 b, f32x4 c) {
  return __builtin_amdgcn_mfma_f32_16x16x32_bf16(a, b, c, 0, 0, 0);
}
__device__ __forceinline__ f32x4 f4zero() { f32x4 z = {0.f, 0.f, 0.f, 0.f}; return z; }

__device__ __forceinline__ bf16x8 cvt8(const float* __restrict__ p) {
  f32x4 x0 = *(const f32x4*)p;
  f32x4 x1 = *(const f32x4*)(p + 4);
  bf16x8 t;
  t[0] = (short)f2bf(x0[0]); t[1] = (short)f2bf(x0[1]);
  t[2] = (short)f2bf(x0[2]); t[3] = (short)f2bf(x0[3]);
  t[4] = (short)f2bf(x1[0]); t[5] = (short)f2bf(x1[1]);
  t[6] = (short)f2bf(x1[2]); t[7] = (short)f2bf(x1[3]);
  return t;
}

// ---------------------------------------------------------------------------
// Generic GEMM: Out[M,256] = act(A[M,256] @ W[256,256] + bias)
// ---------------------------------------------------------------------------
template<int ADT, int ACT, int ODT>
__global__ __launch_bounds__(256) void gemm_k256(
    const void* __restrict__ Av, const unsigned short* __restrict__ Wt,
    const float* __restrict__ bias, void* __restrict__ Outv, int M)
{
  const int m0  = (int)blockIdx.x * 64;
  const int tid = (int)threadIdx.x;
  const int w   = tid >> 6;
  const int l   = tid & 63;
  const int lr  = l & 15;
  const int g   = l >> 4;

  f32x4 acc[4][4];
#pragma unroll
  for (int a = 0; a < 4; ++a)
#pragma unroll
    for (int b = 0; b < 4; ++b) acc[a][b] = f4zero();

#pragma unroll
  for (int ks = 0; ks < 8; ++ks) {
    const int kb = ks * 32 + g * 8;
    bf16x8 af[4], bfr[4];
#pragma unroll
    for (int mf = 0; mf < 4; ++mf) {
      int row = m0 + mf * 16 + lr;
      if (row >= M) row = M - 1;
      if (ADT == 0)
        af[mf] = *(const bf16x8*)((const unsigned short*)Av + (size_t)row * 256 + kb);
      else
        af[mf] = cvt8((const float*)Av + (size_t)row * 256 + kb);
    }
#pragma unroll
    for (int nf = 0; nf < 4; ++nf) {
      const int col = w * 64 + nf * 16 + lr;
      bfr[nf] = *(const bf16x8*)(Wt + (size_t)col * 256 + kb);
    }
#pragma unroll
    for (int mf = 0; mf < 4; ++mf)
#pragma unroll
      for (int nf = 0; nf < 4; ++nf)
        acc[mf][nf] = MFMA(af[mf], bfr[nf], acc[mf][nf]);
  }

#pragma unroll
  for (int nf = 0; nf < 4; ++nf) {
    const int col = w * 64 + nf * 16 + lr;
    const float bs = bias[col];
#pragma unroll
    for (int mf = 0; mf < 4; ++mf) {
#pragma unroll
      for (int i = 0; i < 4; ++i) {
        const int row = m0 + mf * 16 + g * 4 + i;
        if (row < M) {
          float x = acc[mf][nf][i] + bs;
          if (ACT) x = sspf(x);
          if (ODT == 0)
            ((unsigned short*)Outv)[(size_t)row * 256 + col] = f2bf(x);
          else
            ((float*)Outv)[(size_t)row * 256 + col] = x;
        }
      }
    }
  }
}

// ---------------------------------------------------------------------------
// Counting sort by dst.
// ---------------------------------------------------------------------------
__global__ __launch_bounds__(256) void hist_dst(const int* __restrict__ eidx,
                                                int* __restrict__ cnt)
{
  const int e = (int)blockIdx.x * 256 + (int)threadIdx.x;
  atomicAdd(&cnt[eidx[N_EDGES + e]], 1);
}

__global__ __launch_bounds__(1024) void scan_cnt(const int* __restrict__ cnt,
                                                 int* __restrict__ cursor)
{
  __shared__ int part[1024];
  const int t = (int)threadIdx.x;
  const int base = t * 49;
  int s = 0;
#pragma unroll 7
  for (int j = 0; j < 49; ++j) {
    const int idx = base + j;
    if (idx < N_NODES) s += cnt[idx];
  }
  part[t] = s;
  __syncthreads();
  for (int off = 1; off < 1024; off <<= 1) {
    int v = 0;
    if (t >= off) v = part[t - off];
    __syncthreads();
    part[t] += v;
    __syncthreads();
  }
  int run = (t == 0) ? 0 : part[t - 1];
#pragma unroll 7
  for (int j = 0; j < 49; ++j) {
    const int idx = base + j;
    if (idx < N_NODES) { cursor[idx] = run; run += cnt[idx]; }
  }
}

// fast path: rank[e] (coalesced), srcs/dsts in sorted order (scattered)
__global__ __launch_bounds__(256) void scatter_rank(
    const int* __restrict__ eidx, int* __restrict__ cursor,
    int* __restrict__ rank, int* __restrict__ srcs, int* __restrict__ dsts)
{
  const int e = (int)blockIdx.x * 256 + (int)threadIdx.x;
  const int d = eidx[N_EDGES + e];
  const int pos = atomicAdd(&cursor[d], 1);
  rank[e]   = pos;
  srcs[pos] = eidx[e];
  dsts[pos] = d;
}

// fallback path: perm + Cf + srcs + dsts (R3)
__global__ __launch_bounds__(256) void scatter_perm_fb(
    const int* __restrict__ eidx, const float* __restrict__ ew,
    int* __restrict__ cursor, int* __restrict__ perm,
    float* __restrict__ Cf, int* __restrict__ srcs, int* __restrict__ dsts)
{
  const int e = (int)blockIdx.x * 256 + (int)threadIdx.x;
  const int d = eidx[N_EDGES + e];
  const int pos = atomicAdd(&cursor[d], 1);
  perm[pos] = e;
  Cf[pos]   = 0.5f * (__cosf(ew[e] * 0.31415926535897931f) + 1.0f);
  srcs[pos] = eidx[e];
  dsts[pos] = d;
}

// fallback: eattr_s[i][64] bf16 = eattr[perm[i]][k], 0-padded
__global__ __launch_bounds__(256) void prep_eattr(
    const float* __restrict__ ea, const int* __restrict__ perm,
    unsigned short* __restrict__ out)
{
  const int t = (int)blockIdx.x * 256 + (int)threadIdx.x;
  const int i = t >> 3, j = t & 7;
  const int p = perm[i];
  const float* ap = ea + (size_t)p * 50 + j * 8;
  bf16x8 v;
  if (j < 6) {
    f32x2 a0 = *(const f32x2*)(ap);
    f32x2 a1 = *(const f32x2*)(ap + 2);
    f32x2 a2 = *(const f32x2*)(ap + 4);
    f32x2 a3 = *(const f32x2*)(ap + 6);
    v[0] = (short)f2bf(a0[0]); v[1] = (short)f2bf(a0[1]);
    v[2] = (short)f2bf(a1[0]); v[3] = (short)f2bf(a1[1]);
    v[4] = (short)f2bf(a2[0]); v[5] = (short)f2bf(a2[1]);
    v[6] = (short)f2bf(a3[0]); v[7] = (short)f2bf(a3[1]);
  } else if (j == 6) {
    f32x2 a0 = *(const f32x2*)(ap);
    v[0] = (short)f2bf(a0[0]); v[1] = (short)f2bf(a0[1]);
    v[2] = 0; v[3] = 0; v[4] = 0; v[5] = 0; v[6] = 0; v[7] = 0;
  } else {
    v[0] = 0; v[1] = 0; v[2] = 0; v[3] = 0; v[4] = 0; v[5] = 0; v[6] = 0; v[7] = 0;
  }
  *(bf16x8*)(out + (size_t)i * 64 + j * 8) = v;
}

// ---------------------------------------------------------------------------
// FAST PATH kernel A: edge MLP in NATURAL edge order, 64 edges/block.
//   Wf = ssp(ssp(eattr@m1+b1)@m2+b2) * C(ew)  -> bf16, written to sorted
//   position rank[e] (full 512B rows, nontemporal).
// ---------------------------------------------------------------------------
__global__ __launch_bounds__(256) void edge_mlp(
    const float* __restrict__ eattr, const float* __restrict__ ew,
    const int* __restrict__ rank,
    const unsigned short* __restrict__ m1t, const float* __restrict__ m1b,
    const unsigned short* __restrict__ m2t, const float* __restrict__ m2b,
    unsigned short* __restrict__ Wf)
{
  __shared__ unsigned short t_lds[64 * 256];  // 32 KiB; t, then Wf
  __shared__ float Cs[64];
  __shared__ int s_rank[64];

  const int e0  = (int)blockIdx.x * 64;
  const int tid = (int)threadIdx.x;
  if (tid < 64) {
    Cs[tid]     = 0.5f * (__cosf(ew[e0 + tid] * 0.31415926535897931f) + 1.0f);
    s_rank[tid] = rank[e0 + tid];
  }

  const int w = tid >> 6, l = tid & 63, lr = l & 15, g = l >> 4;

  f32x4 acc[4][4];
#pragma unroll
  for (int a = 0; a < 4; ++a)
#pragma unroll
    for (int b = 0; b < 4; ++b) acc[a][b] = f4zero();

  // ---- stage 1: K=50 padded to 64 (m1t zero-padded; A lanes k>=50 zeroed)
#pragma unroll
  for (int ks = 0; ks < 2; ++ks) {
    const int kb = ks * 32 + g * 8;
    bf16x8 af[4], bfr[4];
#pragma unroll
    for (int mf = 0; mf < 4; ++mf) {
      const int row = e0 + mf * 16 + lr;                 // < E (E%64==0)
      const float* ap = eattr + (size_t)row * 50 + kb;
      bf16x8 t;
      if (kb + 8 <= 50) {                                // 8B-aligned in-row
        f32x2 x0 = *(const f32x2*)(ap);
        f32x2 x1 = *(const f32x2*)(ap + 2);
        f32x2 x2 = *(const f32x2*)(ap + 4);
        f32x2 x3 = *(const f32x2*)(ap + 6);
        t[0] = (short)f2bf(x0[0]); t[1] = (short)f2bf(x0[1]);
        t[2] = (short)f2bf(x1[0]); t[3] = (short)f2bf(x1[1]);
        t[4] = (short)f2bf(x2[0]); t[5] = (short)f2bf(x2[1]);
        t[6] = (short)f2bf(x3[0]); t[7] = (short)f2bf(x3[1]);
      } else if (kb < 50) {                              // kb=48: 2 valid
#pragma unroll
        for (int j = 0; j < 8; ++j)
          t[j] = (kb + j < 50) ? (short)f2bf(ap[j]) : (short)0;
      } else {                                           // kb=56: all pad
#pragma unroll
        for (int j = 0; j < 8; ++j) t[j] = 0;
      }
      af[mf] = t;
    }
#pragma unroll
    for (int nf = 0; nf < 4; ++nf) {
      const int col = w * 64 + nf * 16 + lr;
      bfr[nf] = *(const bf16x8*)(m1t + col * 64 + kb);
    }
#pragma unroll
    for (int mf = 0; mf < 4; ++mf)
#pragma unroll
      for (int nf = 0; nf < 4; ++nf)
        acc[mf][nf] = MFMA(af[mf], bfr[nf], acc[mf][nf]);
  }

  // ---- epilogue 1: t = ssp(.) -> t_lds (bf16, byte ^= (row&7)<<4)
#pragma unroll
  for (int nf = 0; nf < 4; ++nf) {
    const int col = w * 64 + nf * 16 + lr;
    const float bs = m1b[col];
#pragma unroll
    for (int mf = 0; mf < 4; ++mf)
#pragma unroll
      for (int i = 0; i < 4; ++i) {
        const int r = mf * 16 + g * 4 + i;
        const float x = sspf(acc[mf][nf][i] + bs);
        const int byt = (r * 512 + col * 2) ^ ((r & 7) << 4);
        *(unsigned short*)((char*)t_lds + byt) = f2bf(x);
      }
  }
  __syncthreads();

  // ---- stage 2: K=256
#pragma unroll
  for (int a = 0; a < 4; ++a)
#pragma unroll
    for (int b = 0; b < 4; ++b) acc[a][b] = f4zero();

#pragma unroll
  for (int ks = 0; ks < 8; ++ks) {
    const int kb = ks * 32 + g * 8;
    bf16x8 af[4], bfr[4];
#pragma unroll
    for (int mf = 0; mf < 4; ++mf) {
      const int r = mf * 16 + lr;
      const int byt = (r * 512 + kb * 2) ^ ((r & 7) << 4);
      af[mf] = *(const bf16x8*)((const char*)t_lds + byt);
    }
#pragma unroll
    for (int nf = 0; nf < 4; ++nf) {
      const int col = w * 64 + nf * 16 + lr;
      bfr[nf] = *(const bf16x8*)(m2t + (size_t)col * 256 + kb);
    }
#pragma unroll
    for (int mf = 0; mf < 4; ++mf)
#pragma unroll
      for (int nf = 0; nf < 4; ++nf)
        acc[mf][nf] = MFMA(af[mf], bfr[nf], acc[mf][nf]);
  }

  __syncthreads();  // stage-2 reads complete before overwrite

  // ---- epilogue 2: Wf = ssp(acc+b2)*C -> t_lds
#pragma unroll
  for (int nf = 0; nf < 4; ++nf) {
    const int col = w * 64 + nf * 16 + lr;
    const float bs = m2b[col];
#pragma unroll
    for (int mf = 0; mf < 4; ++mf) {
#pragma unroll
      for (int i = 0; i < 4; ++i) {
        const int er = mf * 16 + g * 4 + i;
        const float wf = sspf(acc[mf][nf][i] + bs) * Cs[er];
        const int byt = (er * 512 + col * 2) ^ ((er & 7) << 4);
        *(unsigned short*)((char*)t_lds + byt) = f2bf(wf);
      }
    }
  }
  __syncthreads();

  // ---- copy-out: wave q handles rows 16q..16q+15; lane owns 4 cols.
  // Each wave-store = one full 512B row at sorted position (nontemporal).
  {
    const int q  = tid >> 6;
    const int c4 = (tid & 63) * 4;
#pragma unroll
    for (int rr = 0; rr < 16; ++rr) {
      const int r = q * 16 + rr;
      const int byt = (r * 512 + c4 * 2) ^ ((r & 7) << 4);
      const unsigned long long v =
          *(const unsigned long long*)((const char*)t_lds + byt);
      __builtin_nontemporal_store(
          v, (unsigned long long*)(Wf + (size_t)s_rank[r] * 256 + c4));
    }
  }
}

// ---------------------------------------------------------------------------
// FAST PATH kernel B: aggregation over sorted edges, 64/block, no MFMA/LDS
// tile. Wave q owns rows 16q..16q+15; lane owns 4 cols. Wf streamed
// nontemporal; h1 gather (L3-resident, 16x reuse); segmented atomic flush.
// ---------------------------------------------------------------------------
__global__ __launch_bounds__(256) void edge_agg(
    const unsigned short* __restrict__ Wf,
    const int* __restrict__ srcs, const int* __restrict__ dsts,
    const unsigned short* __restrict__ h1, float* __restrict__ agg)
{
  __shared__ int s_src[64], s_dst[65];
  const int e0  = (int)blockIdx.x * 64;
  const int tid = (int)threadIdx.x;
  if (tid < 64) {
    s_src[tid] = srcs[e0 + tid];
    s_dst[tid] = dsts[e0 + tid];
  }
  if (tid == 0)
    s_dst[64] = (e0 + 64 < N_EDGES) ? dsts[e0 + 64] : -1;
  __syncthreads();

  const int q  = tid >> 6;
  const int c4 = (tid & 63) * 4;
  float s0 = 0.f, s1 = 0.f, s2 = 0.f, s3 = 0.f;
#pragma unroll
  for (int rr = 0; rr < 16; ++rr) {
    const int r = q * 16 + rr;
    const unsigned long long wfp = __builtin_nontemporal_load(
        (const unsigned long long*)(Wf + (size_t)(e0 + r) * 256 + c4));
    const unsigned long long xjp =
        *(const unsigned long long*)(h1 + (size_t)s_src[r] * 256 + c4);
    s0 += bf2f((unsigned int)wfp) * bf2f((unsigned int)xjp);
    s1 += bf2f((unsigned int)(wfp >> 16)) * bf2f((unsigned int)(xjp >> 16));
    s2 += bf2f((unsigned int)(wfp >> 32)) * bf2f((unsigned int)(xjp >> 32));
    s3 += bf2f((unsigned int)(wfp >> 48)) * bf2f((unsigned int)(xjp >> 48));
    const int d = s_dst[r];
    if (rr == 15 || s_dst[r + 1] != d) {      // wave-uniform branch
      float* ap = agg + (size_t)d * 256 + c4;
      atomicAdd(ap, s0);
      atomicAdd(ap + 1, s1);
      atomicAdd(ap + 2, s2);
      atomicAdd(ap + 3, s3);
      s0 = 0.f; s1 = 0.f; s2 = 0.f; s3 = 0.f;
    }
  }
}

// ---------------------------------------------------------------------------
// FALLBACK (R3): fused edge pipeline, 64 edges/block (known-good 795us)
// ---------------------------------------------------------------------------
__global__ __launch_bounds__(256) void edge_fused_fb(
    const unsigned short* __restrict__ eattr_s,
    const float* __restrict__ Cf,
    const int* __restrict__ srcs, const int* __restrict__ dsts,
    const unsigned short* __restrict__ m1t, const float* __restrict__ m1b,
    const unsigned short* __restrict__ m2t, const float* __restrict__ m2b,
    const unsigned short* __restrict__ h1, float* __restrict__ agg)
{
  __shared__ unsigned short t_lds[64 * 256];
  __shared__ float Cs[64];
  __shared__ int s_src[64], s_dst[64];

  const int e0  = (int)blockIdx.x * 64;
  const int tid = (int)threadIdx.x;
  if (tid < 64) {
    Cs[tid]    = Cf[e0 + tid];
    s_src[tid] = srcs[e0 + tid];
    s_dst[tid] = dsts[e0 + tid];
  }
  __syncthreads();

  const int w = tid >> 6, l = tid & 63, lr = l & 15, g = l >> 4;

  f32x4 acc[4][4];
#pragma unroll
  for (int a = 0; a < 4; ++a)
#pragma unroll
    for (int b = 0; b < 4; ++b) acc[a][b] = f4zero();

#pragma unroll
  for (int ks = 0; ks < 2; ++ks) {
    const int kb = ks * 32 + g * 8;
    bf16x8 af[4], bfr[4];
#pragma unroll
    for (int mf = 0; mf < 4; ++mf)
      af[mf] = *(const bf16x8*)(eattr_s + (size_t)(e0 + mf * 16 + lr) * 64 + kb);
#pragma unroll
    for (int nf = 0; nf < 4; ++nf) {
      const int col = w * 64 + nf * 16 + lr;
      bfr[nf] = *(const bf16x8*)(m1t + col * 64 + kb);
    }
#pragma unroll
    for (int mf = 0; mf < 4; ++mf)
#pragma unroll
      for (int nf = 0; nf < 4; ++nf)
        acc[mf][nf] = MFMA(af[mf], bfr[nf], acc[mf][nf]);
  }

#pragma unroll
  for (int nf = 0; nf < 4; ++nf) {
    const int col = w * 64 + nf * 16 + lr;
    const float bs = m1b[col];
#pragma unroll
    for (int mf = 0; mf < 4; ++mf)
#pragma unroll
      for (int i = 0; i < 4; ++i) {
        const int r = mf * 16 + g * 4 + i;
        const float x = sspf(acc[mf][nf][i] + bs);
        const int byt = (r * 512 + col * 2) ^ ((r & 7) << 4);
        *(unsigned short*)((char*)t_lds + byt) = f2bf(x);
      }
  }
  __syncthreads();

#pragma unroll
  for (int a = 0; a < 4; ++a)
#pragma unroll
    for (int b = 0; b < 4; ++b) acc[a][b] = f4zero();

#pragma unroll
  for (int ks = 0; ks < 8; ++ks) {
    const int kb = ks * 32 + g * 8;
    bf16x8 af[4], bfr[4];
#pragma unroll
    for (int mf = 0; mf < 4; ++mf) {
      const int r = mf * 16 + lr;
      const int byt = (r * 512 + kb * 2) ^ ((r & 7) << 4);
      af[mf] = *(const bf16x8*)((const char*)t_lds + byt);
    }
#pragma unroll
    for (int nf = 0; nf < 4; ++nf) {
      const int col = w * 64 + nf * 16 + lr;
      bfr[nf] = *(const bf16x8*)(m2t + (size_t)col * 256 + kb);
    }
#pragma unroll
    for (int mf = 0; mf < 4; ++mf)
#pragma unroll
      for (int nf = 0; nf < 4; ++nf)
        acc[mf][nf] = MFMA(af[mf], bfr[nf], acc[mf][nf]);
  }

  __syncthreads();

#pragma unroll
  for (int nf = 0; nf < 4; ++nf) {
    const int col = w * 64 + nf * 16 + lr;
    const float bs = m2b[col];
#pragma unroll
    for (int mf = 0; mf < 4; ++mf) {
#pragma unroll
      for (int i = 0; i < 4; ++i) {
        const int er = mf * 16 + g * 4 + i;
        const float wf = sspf(acc[mf][nf][i] + bs) * Cs[er];
        const int byt = (er * 512 + col * 2) ^ ((er & 7) << 4);
        *(unsigned short*)((char*)t_lds + byt) = f2bf(wf);
      }
    }
  }
  __syncthreads();

  {
    const int half  = tid >> 7;
    const int cp    = tid & 127;
    const int col2  = cp * 2;
    const int rbase = half * 32;
    float s0 = 0.0f, s1 = 0.0f;
#pragma unroll 8
    for (int rr = 0; rr < 32; ++rr) {
      const int r = rbase + rr;
      const int byt = (r * 512 + col2 * 2) ^ ((r & 7) << 4);
      const unsigned int wfp = *(const unsigned int*)((const char*)t_lds + byt);
      const unsigned int xjp =
          *(const unsigned int*)(h1 + (size_t)s_src[r] * 256 + col2);
      s0 += bf2f(wfp) * bf2f(xjp);
      s1 += bf2f(wfp >> 16) * bf2f(xjp >> 16);
      const int d = s_dst[r];
      const bool flush = (rr == 31) || (s_dst[r + 1] != d);
      if (flush) {
        float* ap = agg + (size_t)d * 256 + col2;
        atomicAdd(ap, s0);
        atomicAdd(ap + 1, s1);
        s0 = 0.0f; s1 = 0.0f;
      }
    }
  }
}

// ---------------------------------------------------------------------------
// Transpose + downcast weights
// ---------------------------------------------------------------------------
__global__ __launch_bounds__(256) void prep_weights(
    const float* __restrict__ aw, const float* __restrict__ m1,
    const float* __restrict__ m2, const float* __restrict__ o1,
    const float* __restrict__ o2,
    unsigned short* __restrict__ awt, unsigned short* __restrict__ m1t,
    unsigned short* __restrict__ m2t, unsigned short* __restrict__ o1t,
    unsigned short* __restrict__ o2t)
{
  const int i = (int)blockIdx.x * 256 + (int)threadIdx.x;
  const int c = i >> 8, k = i & 255;
  const int src = k * 256 + c;
  awt[i] = f2bf(aw[src]);
  m2t[i] = f2bf(m2[src]);
  o1t[i] = f2bf(o1[src]);
  o2t[i] = f2bf(o2[src]);
  if (k < 64) m1t[c * 64 + k] = (k < 50) ? f2bf(m1[k * 256 + c]) : (unsigned short)0;
}

extern "C" void kernel_launch(void* const* d_in, const int* in_sizes, int n_in,
                              void* d_out, int out_size, void* d_ws, size_t ws_size,
                              hipStream_t stream)
{
  const float* h    = (const float*)d_in[0];
  const int*   eidx = (const int*)d_in[1];
  const float* ew   = (const float*)d_in[2];
  const float* ea   = (const float*)d_in[3];
  const float* awW  = (const float*)d_in[4];
  const float* awb  = (const float*)d_in[5];
  const float* m1W  = (const float*)d_in[6];
  const float* m1b  = (const float*)d_in[7];
  const float* m2W  = (const float*)d_in[8];
  const float* m2b  = (const float*)d_in[9];
  const float* o1W  = (const float*)d_in[10];
  const float* o1b  = (const float*)d_in[11];
  const float* o2W  = (const float*)d_in[12];
  const float* o2b  = (const float*)d_in[13];

  char* ws = (char*)d_ws;
  unsigned short* h1  = (unsigned short*)ws;                  // 25,600,000
  float*          agg = (float*)(ws + 25600000);              // 51,200,000
  char* wbase = ws + 25600000 + 51200000;                     // 76,800,000
  unsigned short* awt = (unsigned short*)wbase;               // 131072
  unsigned short* m2t = awt + 65536;                          // 131072
  unsigned short* o1t = m2t + 65536;                          // 131072
  unsigned short* o2t = o1t + 65536;                          // 131072
  unsigned short* m1t = o2t + 65536;                          // 32768
  char* p0 = wbase + 4 * 131072 + 32768;                      // 77,357,056
  int* cnt    = (int*)p0;                                     // 200,000
  int* cursor = cnt + N_NODES;                                // 200,000
  int* rank   = cursor + N_NODES;                             // 3,200,000 (fb: perm)
  char* p1 = p0 + 400000 + 3200000;                           // 80,957,056
  float* Cf   = (float*)p1;                                   // 3,200,000 (fb only)
  int*   srcs = (int*)(p1 + 3200000);                         // 3,200,000
  int*   dsts = (int*)(p1 + 6400000);                         // 3,200,000
  char* p2 = p1 + 9600000;                                    // 90,557,056
  unsigned short* eattr_s = (unsigned short*)p2;              // fb: 102,400,000
  unsigned short* Wf_s    = (unsigned short*)p2;              // fast: 409,600,000
  const size_t need_fast = 90557056 + 409600000;              // ~500 MB
  const bool FAST = (ws_size >= need_fast);

  hipMemsetAsync(agg, 0, (size_t)N_NODES * 256 * 4, stream);
  hipMemsetAsync(cnt, 0, (size_t)N_NODES * 4, stream);

  prep_weights<<<256, 256, 0, stream>>>(awW, m1W, m2W, o1W, o2W,
                                        awt, m1t, m2t, o1t, o2t);
  hist_dst<<<N_EDGES / 256, 256, 0, stream>>>(eidx, cnt);
  scan_cnt<<<1, 1024, 0, stream>>>(cnt, cursor);

  if (FAST) {
    scatter_rank<<<N_EDGES / 256, 256, 0, stream>>>(eidx, cursor, rank, srcs, dsts);
    // h1 = h @ aw_W + aw_b
    gemm_k256<1, 0, 0><<<(N_NODES + 63) / 64, 256, 0, stream>>>(h, awt, awb, h1, N_NODES);
    edge_mlp<<<N_EDGES / 64, 256, 0, stream>>>(ea, ew, rank, m1t, m1b, m2t, m2b, Wf_s);
    edge_agg<<<N_EDGES / 64, 256, 0, stream>>>(Wf_s, srcs, dsts, h1, agg);
  } else {
    scatter_perm_fb<<<N_EDGES / 256, 256, 0, stream>>>(eidx, ew, cursor, rank,
                                                       Cf, srcs, dsts);
    prep_eattr<<<N_EDGES * 8 / 256, 256, 0, stream>>>(ea, rank, eattr_s);
    gemm_k256<1, 0, 0><<<(N_NODES + 63) / 64, 256, 0, stream>>>(h, awt, awb, h1, N_NODES);
    edge_fused_fb<<<N_EDGES / 64, 256, 0, stream>>>(
        eattr_s, Cf, srcs, dsts, m1t, m1b, m2t, m2b, h1, agg);
  }

  // o = ssp(agg @ o1_W + o1_b)   (into h1's buffer)
  gemm_k256<1, 1, 0><<<(N_NODES + 63) / 64, 256, 0, stream>>>(agg, o1t, o1b, h1, N_NODES);
  // out = o @ o2_W + o2_b
  gemm_k256<0, 0, 1><<<(N_NODES + 63) / 64, 256, 0, stream>>>(h1, o2t, o2b, d_out, N_NODES);
}

// Round 7
// 1164.765 us; speedup vs baseline: 1.1199x; 1.1199x over previous
//
#include <hip/hip_runtime.h>

#define N_NODES 50000
#define N_EDGES 800000

typedef __attribute__((ext_vector_type(8))) short bf16x8;
typedef __attribute__((ext_vector_type(4))) float f32x4;
typedef __attribute__((ext_vector_type(2))) float f32x2;

__device__ __forceinline__ float bf2f(unsigned int u) {
  union { unsigned int u; float f; } c; c.u = (u & 0xffffu) << 16; return c.f;
}
// round-half-up: same half-ulp bound as RNE (differs only on exact ties)
__device__ __forceinline__ unsigned short f2bf(float f) {
  union { float f; unsigned int u; } c; c.f = f;
  return (unsigned short)((c.u + 0x8000u) >> 16);
}
__device__ __forceinline__ float sspf(float x) {
  return fmaxf(x, 0.0f) + __logf(1.0f + __expf(-fabsf(x))) - 0.69314718055994531f;
}
__device__ __forceinline__ f32x4 MFMA(bf16x8 a, bf16x8 b, f32x4 c) {
  return __builtin_amdgcn_mfma_f32_16x16x32_bf16(a, b, c, 0, 0, 0);
}
__device__ __forceinline__ f32x4 f4zero() { f32x4 z = {0.f, 0.f, 0.f, 0.f}; return z; }

__device__ __forceinline__ bf16x8 cvt8(const float* __restrict__ p) {
  f32x4 x0 = *(const f32x4*)p;
  f32x4 x1 = *(const f32x4*)(p + 4);
  bf16x8 t;
  t[0] = (short)f2bf(x0[0]); t[1] = (short)f2bf(x0[1]);
  t[2] = (short)f2bf(x0[2]); t[3] = (short)f2bf(x0[3]);
  t[4] = (short)f2bf(x1[0]); t[5] = (short)f2bf(x1[1]);
  t[6] = (short)f2bf(x1[2]); t[7] = (short)f2bf(x1[3]);
  return t;
}

// ---------------------------------------------------------------------------
// Generic GEMM: Out[M,256] = act(A[M,256] @ W[256,256] + bias)
// ---------------------------------------------------------------------------
template<int ADT, int ACT, int ODT>
__global__ __launch_bounds__(256) void gemm_k256(
    const void* __restrict__ Av, const unsigned short* __restrict__ Wt,
    const float* __restrict__ bias, void* __restrict__ Outv, int M)
{
  const int m0  = (int)blockIdx.x * 64;
  const int tid = (int)threadIdx.x;
  const int w   = tid >> 6;
  const int l   = tid & 63;
  const int lr  = l & 15;
  const int g   = l >> 4;

  f32x4 acc[4][4];
#pragma unroll
  for (int a = 0; a < 4; ++a)
#pragma unroll
    for (int b = 0; b < 4; ++b) acc[a][b] = f4zero();

#pragma unroll
  for (int ks = 0; ks < 8; ++ks) {
    const int kb = ks * 32 + g * 8;
    bf16x8 af[4], bfr[4];
#pragma unroll
    for (int mf = 0; mf < 4; ++mf) {
      int row = m0 + mf * 16 + lr;
      if (row >= M) row = M - 1;
      if (ADT == 0)
        af[mf] = *(const bf16x8*)((const unsigned short*)Av + (size_t)row * 256 + kb);
      else
        af[mf] = cvt8((const float*)Av + (size_t)row * 256 + kb);
    }
#pragma unroll
    for (int nf = 0; nf < 4; ++nf) {
      const int col = w * 64 + nf * 16 + lr;
      bfr[nf] = *(const bf16x8*)(Wt + (size_t)col * 256 + kb);
    }
#pragma unroll
    for (int mf = 0; mf < 4; ++mf)
#pragma unroll
      for (int nf = 0; nf < 4; ++nf)
        acc[mf][nf] = MFMA(af[mf], bfr[nf], acc[mf][nf]);
  }

#pragma unroll
  for (int nf = 0; nf < 4; ++nf) {
    const int col = w * 64 + nf * 16 + lr;
    const float bs = bias[col];
#pragma unroll
    for (int mf = 0; mf < 4; ++mf) {
#pragma unroll
      for (int i = 0; i < 4; ++i) {
        const int row = m0 + mf * 16 + g * 4 + i;
        if (row < M) {
          float x = acc[mf][nf][i] + bs;
          if (ACT) x = sspf(x);
          if (ODT == 0)
            ((unsigned short*)Outv)[(size_t)row * 256 + col] = f2bf(x);
          else
            ((float*)Outv)[(size_t)row * 256 + col] = x;
        }
      }
    }
  }
}

// ---------------------------------------------------------------------------
// Counting sort by dst.
// ---------------------------------------------------------------------------
__global__ __launch_bounds__(256) void hist_dst(const int* __restrict__ eidx,
                                                int* __restrict__ cnt)
{
  const int e = (int)blockIdx.x * 256 + (int)threadIdx.x;
  atomicAdd(&cnt[eidx[N_EDGES + e]], 1);
}

__global__ __launch_bounds__(1024) void scan_cnt(const int* __restrict__ cnt,
                                                 int* __restrict__ cursor)
{
  __shared__ int part[1024];
  const int t = (int)threadIdx.x;
  const int base = t * 49;
  int s = 0;
#pragma unroll 7
  for (int j = 0; j < 49; ++j) {
    const int idx = base + j;
    if (idx < N_NODES) s += cnt[idx];
  }
  part[t] = s;
  __syncthreads();
  for (int off = 1; off < 1024; off <<= 1) {
    int v = 0;
    if (t >= off) v = part[t - off];
    __syncthreads();
    part[t] += v;
    __syncthreads();
  }
  int run = (t == 0) ? 0 : part[t - 1];
#pragma unroll 7
  for (int j = 0; j < 49; ++j) {
    const int idx = base + j;
    if (idx < N_NODES) { cursor[idx] = run; run += cnt[idx]; }
  }
}

__global__ __launch_bounds__(256) void scatter_rank(
    const int* __restrict__ eidx, int* __restrict__ cursor,
    int* __restrict__ rank, int* __restrict__ srcs, int* __restrict__ dsts)
{
  const int e = (int)blockIdx.x * 256 + (int)threadIdx.x;
  const int d = eidx[N_EDGES + e];
  const int pos = atomicAdd(&cursor[d], 1);
  rank[e]   = pos;
  srcs[pos] = eidx[e];
  dsts[pos] = d;
}

// ---------------------------------------------------------------------------
// Edge MLP, 64 edges/block, 512 threads (8 waves), wave owns 32 cols.
// Phase 0 stages eattr f32->bf16 once into LDS (8x dedup vs per-wave).
// VGPR target <=64 -> 4 blocks/CU (32 waves). Output Wf (bf16) to sorted
// row rank[e], full 512B rows, nontemporal.
// ---------------------------------------------------------------------------
__global__ __launch_bounds__(512, 8) void edge_mlp512(
    const float* __restrict__ eattr, const float* __restrict__ ew,
    const int* __restrict__ rank,
    const unsigned short* __restrict__ m1t, const float* __restrict__ m1b,
    const unsigned short* __restrict__ m2t, const float* __restrict__ m2b,
    unsigned short* __restrict__ Wf)
{
  __shared__ unsigned short t_lds[64 * 256];  // 32 KiB; ea-tile, t, then Wf
  __shared__ float Cs[64];
  __shared__ int s_rank[64];
  unsigned short* ea_lds = t_lds;             // [64][64] bf16 alias (8 KiB)

  const int e0  = (int)blockIdx.x * 64;
  const int tid = (int)threadIdx.x;

  // ---- phase 0: stage eattr rows e0..e0+63 -> bf16 LDS, swizzled
  {
    const int r  = tid >> 3;                  // 0..63
    const int oc = tid & 7;                   // k-octet
    const float* ap = eattr + (size_t)(e0 + r) * 50 + oc * 8;
    bf16x8 v;
    if (oc < 6) {
      f32x2 a0 = *(const f32x2*)(ap);
      f32x2 a1 = *(const f32x2*)(ap + 2);
      f32x2 a2 = *(const f32x2*)(ap + 4);
      f32x2 a3 = *(const f32x2*)(ap + 6);
      v[0] = (short)f2bf(a0[0]); v[1] = (short)f2bf(a0[1]);
      v[2] = (short)f2bf(a1[0]); v[3] = (short)f2bf(a1[1]);
      v[4] = (short)f2bf(a2[0]); v[5] = (short)f2bf(a2[1]);
      v[6] = (short)f2bf(a3[0]); v[7] = (short)f2bf(a3[1]);
    } else if (oc == 6) {
      f32x2 a0 = *(const f32x2*)(ap);
      v[0] = (short)f2bf(a0[0]); v[1] = (short)f2bf(a0[1]);
      v[2] = 0; v[3] = 0; v[4] = 0; v[5] = 0; v[6] = 0; v[7] = 0;
    } else {
      v[0] = 0; v[1] = 0; v[2] = 0; v[3] = 0; v[4] = 0; v[5] = 0; v[6] = 0; v[7] = 0;
    }
    const int byt = r * 128 + ((oc * 16) ^ ((r & 7) << 4));
    *(bf16x8*)((char*)ea_lds + byt) = v;
  }
  if (tid < 64) {
    Cs[tid]     = 0.5f * (__cosf(ew[e0 + tid] * 0.31415926535897931f) + 1.0f);
    s_rank[tid] = rank[e0 + tid];
  }
  __syncthreads();

  const int w  = tid >> 6;                    // wave 0..7
  const int l  = tid & 63;
  const int lr = l & 15;
  const int g  = l >> 4;
  const int c0 = w * 32;                      // wave's column base

  f32x4 acc[4][2];
#pragma unroll
  for (int a = 0; a < 4; ++a)
#pragma unroll
    for (int b = 0; b < 2; ++b) acc[a][b] = f4zero();

  // ---- stage 1: K=64 (k>=50 zero-padded both sides)
#pragma unroll
  for (int ks = 0; ks < 2; ++ks) {
    const int kb = ks * 32 + g * 8;           // element k-base
    bf16x8 bfr[2];
#pragma unroll
    for (int nf = 0; nf < 2; ++nf)
      bfr[nf] = *(const bf16x8*)(m1t + (c0 + nf * 16 + lr) * 64 + kb);
#pragma unroll
    for (int mf = 0; mf < 4; ++mf) {
      const int r = mf * 16 + lr;
      const int byt = r * 128 + ((kb * 2) ^ ((r & 7) << 4));
      const bf16x8 af = *(const bf16x8*)((const char*)ea_lds + byt);
      __builtin_amdgcn_s_setprio(1);
      acc[mf][0] = MFMA(af, bfr[0], acc[mf][0]);
      acc[mf][1] = MFMA(af, bfr[1], acc[mf][1]);
      __builtin_amdgcn_s_setprio(0);
    }
  }
  __syncthreads();   // all ea_lds reads done before ep1 overwrites region

  // ---- epilogue 1: t = ssp(.) -> t_lds (bf16, byte ^= (r&7)<<4)
#pragma unroll
  for (int nf = 0; nf < 2; ++nf) {
    const int col = c0 + nf * 16 + lr;
    const float bs = m1b[col];
#pragma unroll
    for (int mf = 0; mf < 4; ++mf)
#pragma unroll
      for (int i = 0; i < 4; ++i) {
        const int r = mf * 16 + g * 4 + i;
        const float x = sspf(acc[mf][nf][i] + bs);
        const int byt = (r * 512 + col * 2) ^ ((r & 7) << 4);
        *(unsigned short*)((char*)t_lds + byt) = f2bf(x);
      }
  }
  __syncthreads();

  // ---- stage 2: K=256
#pragma unroll
  for (int a = 0; a < 4; ++a)
#pragma unroll
    for (int b = 0; b < 2; ++b) acc[a][b] = f4zero();

#pragma unroll
  for (int ks = 0; ks < 8; ++ks) {
    const int kb = ks * 32 + g * 8;
    bf16x8 bfr[2];
#pragma unroll
    for (int nf = 0; nf < 2; ++nf)
      bfr[nf] = *(const bf16x8*)(m2t + (size_t)(c0 + nf * 16 + lr) * 256 + kb);
#pragma unroll
    for (int mf = 0; mf < 4; ++mf) {
      const int r = mf * 16 + lr;
      const int byt = (r * 512 + kb * 2) ^ ((r & 7) << 4);
      const bf16x8 af = *(const bf16x8*)((const char*)t_lds + byt);
      __builtin_amdgcn_s_setprio(1);
      acc[mf][0] = MFMA(af, bfr[0], acc[mf][0]);
      acc[mf][1] = MFMA(af, bfr[1], acc[mf][1]);
      __builtin_amdgcn_s_setprio(0);
    }
  }
  __syncthreads();   // stage-2 reads complete block-wide before overwrite

  // ---- epilogue 2: Wf = ssp(acc+b2)*C -> t_lds (same swizzle)
#pragma unroll
  for (int nf = 0; nf < 2; ++nf) {
    const int col = c0 + nf * 16 + lr;
    const float bs = m2b[col];
#pragma unroll
    for (int mf = 0; mf < 4; ++mf)
#pragma unroll
      for (int i = 0; i < 4; ++i) {
        const int er = mf * 16 + g * 4 + i;
        const float wf = sspf(acc[mf][nf][i] + bs) * Cs[er];
        const int byt = (er * 512 + col * 2) ^ ((er & 7) << 4);
        *(unsigned short*)((char*)t_lds + byt) = f2bf(wf);
      }
  }
  __syncthreads();

  // ---- copy-out: wave w rows 8w..8w+7; lane owns 4 cols -> 512B row stores
  {
    const int c4 = l * 4;
#pragma unroll
    for (int rr = 0; rr < 8; ++rr) {
      const int r = w * 8 + rr;
      const int byt = (r * 512 + c4 * 2) ^ ((r & 7) << 4);
      const unsigned long long v =
          *(const unsigned long long*)((const char*)t_lds + byt);
      __builtin_nontemporal_store(
          v, (unsigned long long*)(Wf + (size_t)s_rank[r] * 256 + c4));
    }
  }
}

// ---------------------------------------------------------------------------
// Aggregation over sorted edges, 256 edges/block, wave owns 64 rows,
// lane owns 4 cols. 2-deep prefetch ahead of segmented atomic flush.
// ---------------------------------------------------------------------------
__global__ __launch_bounds__(256) void edge_agg(
    const unsigned short* __restrict__ Wf,
    const int* __restrict__ srcs, const int* __restrict__ dsts,
    const unsigned short* __restrict__ h1, float* __restrict__ agg)
{
  __shared__ int s_src[256], s_dst[257];
  const int e0  = (int)blockIdx.x * 256;
  const int tid = (int)threadIdx.x;
  s_src[tid] = srcs[e0 + tid];
  s_dst[tid] = dsts[e0 + tid];
  if (tid == 0)
    s_dst[256] = (e0 + 256 < N_EDGES) ? dsts[e0 + 256] : -1;
  __syncthreads();

  const int q     = tid >> 6;
  const int c4    = (tid & 63) * 4;
  const int rbase = q * 64;

  float s0 = 0.f, s1 = 0.f, s2 = 0.f, s3 = 0.f;
  unsigned long long wf_n = __builtin_nontemporal_load(
      (const unsigned long long*)(Wf + (size_t)(e0 + rbase) * 256 + c4));
  unsigned long long xj_n =
      *(const unsigned long long*)(h1 + (size_t)s_src[rbase] * 256 + c4);

#pragma unroll 8
  for (int rr = 0; rr < 64; ++rr) {
    const int r = rbase + rr;
    const unsigned long long wfp = wf_n;
    const unsigned long long xjp = xj_n;
    if (rr < 63) {
      wf_n = __builtin_nontemporal_load(
          (const unsigned long long*)(Wf + (size_t)(e0 + r + 1) * 256 + c4));
      xj_n = *(const unsigned long long*)(h1 + (size_t)s_src[r + 1] * 256 + c4);
    }
    s0 += bf2f((unsigned int)wfp) * bf2f((unsigned int)xjp);
    s1 += bf2f((unsigned int)(wfp >> 16)) * bf2f((unsigned int)(xjp >> 16));
    s2 += bf2f((unsigned int)(wfp >> 32)) * bf2f((unsigned int)(xjp >> 32));
    s3 += bf2f((unsigned int)(wfp >> 48)) * bf2f((unsigned int)(xjp >> 48));
    const int d = s_dst[r];
    if (rr == 63 || s_dst[r + 1] != d) {      // wave-uniform branch
      float* ap = agg + (size_t)d * 256 + c4;
      atomicAdd(ap, s0);
      atomicAdd(ap + 1, s1);
      atomicAdd(ap + 2, s2);
      atomicAdd(ap + 3, s3);
      s0 = 0.f; s1 = 0.f; s2 = 0.f; s3 = 0.f;
    }
  }
}

// ---------------------------------------------------------------------------
// Transpose + downcast weights
// ---------------------------------------------------------------------------
__global__ __launch_bounds__(256) void prep_weights(
    const float* __restrict__ aw, const float* __restrict__ m1,
    const float* __restrict__ m2, const float* __restrict__ o1,
    const float* __restrict__ o2,
    unsigned short* __restrict__ awt, unsigned short* __restrict__ m1t,
    unsigned short* __restrict__ m2t, unsigned short* __restrict__ o1t,
    unsigned short* __restrict__ o2t)
{
  const int i = (int)blockIdx.x * 256 + (int)threadIdx.x;
  const int c = i >> 8, k = i & 255;
  const int src = k * 256 + c;
  awt[i] = f2bf(aw[src]);
  m2t[i] = f2bf(m2[src]);
  o1t[i] = f2bf(o1[src]);
  o2t[i] = f2bf(o2[src]);
  if (k < 64) m1t[c * 64 + k] = (k < 50) ? f2bf(m1[k * 256 + c]) : (unsigned short)0;
}

extern "C" void kernel_launch(void* const* d_in, const int* in_sizes, int n_in,
                              void* d_out, int out_size, void* d_ws, size_t ws_size,
                              hipStream_t stream)
{
  const float* h    = (const float*)d_in[0];
  const int*   eidx = (const int*)d_in[1];
  const float* ew   = (const float*)d_in[2];
  const float* ea   = (const float*)d_in[3];
  const float* awW  = (const float*)d_in[4];
  const float* awb  = (const float*)d_in[5];
  const float* m1W  = (const float*)d_in[6];
  const float* m1b  = (const float*)d_in[7];
  const float* m2W  = (const float*)d_in[8];
  const float* m2b  = (const float*)d_in[9];
  const float* o1W  = (const float*)d_in[10];
  const float* o1b  = (const float*)d_in[11];
  const float* o2W  = (const float*)d_in[12];
  const float* o2b  = (const float*)d_in[13];

  char* ws = (char*)d_ws;
  unsigned short* h1  = (unsigned short*)ws;                  // 25,600,000
  float*          agg = (float*)(ws + 25600000);              // 51,200,000
  char* wbase = ws + 25600000 + 51200000;                     // 76,800,000
  unsigned short* awt = (unsigned short*)wbase;               // 131072
  unsigned short* m2t = awt + 65536;                          // 131072
  unsigned short* o1t = m2t + 65536;                          // 131072
  unsigned short* o2t = o1t + 65536;                          // 131072
  unsigned short* m1t = o2t + 65536;                          // 32768
  char* p0 = wbase + 4 * 131072 + 32768;                      // 77,357,056
  int* cnt    = (int*)p0;                                     // 200,000
  int* cursor = cnt + N_NODES;                                // 200,000
  int* rank   = cursor + N_NODES;                             // 3,200,000
  char* p1 = p0 + 400000 + 3200000;                           // 80,957,056
  int*   srcs = (int*)(p1 + 3200000);                         // 3,200,000
  int*   dsts = (int*)(p1 + 6400000);                         // 3,200,000
  unsigned short* Wf_s = (unsigned short*)(p1 + 9600000);     // 409,600,000
  // total need ~500.2 MB — proven available (R5 fast path ran)

  hipMemsetAsync(agg, 0, (size_t)N_NODES * 256 * 4, stream);
  hipMemsetAsync(cnt, 0, (size_t)N_NODES * 4, stream);

  prep_weights<<<256, 256, 0, stream>>>(awW, m1W, m2W, o1W, o2W,
                                        awt, m1t, m2t, o1t, o2t);
  hist_dst<<<N_EDGES / 256, 256, 0, stream>>>(eidx, cnt);
  scan_cnt<<<1, 1024, 0, stream>>>(cnt, cursor);
  scatter_rank<<<N_EDGES / 256, 256, 0, stream>>>(eidx, cursor, rank, srcs, dsts);

  // edge filter MLP -> Wf (sorted, bf16)
  edge_mlp512<<<N_EDGES / 64, 512, 0, stream>>>(ea, ew, rank,
                                                m1t, m1b, m2t, m2b, Wf_s);
  // h1 = h @ aw_W + aw_b  (bf16 out)
  gemm_k256<1, 0, 0><<<(N_NODES + 63) / 64, 256, 0, stream>>>(h, awt, awb, h1, N_NODES);
  // CFConv aggregation
  edge_agg<<<N_EDGES / 256, 256, 0, stream>>>(Wf_s, srcs, dsts, h1, agg);
  // o = ssp(agg @ o1_W + o1_b)   (into h1's buffer)
  gemm_k256<1, 1, 0><<<(N_NODES + 63) / 64, 256, 0, stream>>>(agg, o1t, o1b, h1, N_NODES);
  // out = o @ o2_W + o2_b
  gemm_k256<0, 0, 1><<<(N_NODES + 63) / 64, 256, 0, stream>>>(h1, o2t, o2b, d_out, N_NODES);
}

// Round 8
// 929.133 us; speedup vs baseline: 1.4039x; 1.2536x over previous
//
#include <hip/hip_runtime.h>

#define N_NODES 50000
#define N_EDGES 800000

typedef __attribute__((ext_vector_type(8))) short bf16x8;
typedef __attribute__((ext_vector_type(4))) float f32x4;
typedef __attribute__((ext_vector_type(2))) float f32x2;

__device__ __forceinline__ float bf2f(unsigned int u) {
  union { unsigned int u; float f; } c; c.u = (u & 0xffffu) << 16; return c.f;
}
// round-half-up: same half-ulp bound as RNE (differs only on exact ties)
__device__ __forceinline__ unsigned short f2bf(float f) {
  union { float f; unsigned int u; } c; c.f = f;
  return (unsigned short)((c.u + 0x8000u) >> 16);
}
__device__ __forceinline__ float sspf(float x) {
  return fmaxf(x, 0.0f) + __logf(1.0f + __expf(-fabsf(x))) - 0.69314718055994531f;
}
__device__ __forceinline__ f32x4 MFMA(bf16x8 a, bf16x8 b, f32x4 c) {
  return __builtin_amdgcn_mfma_f32_16x16x32_bf16(a, b, c, 0, 0, 0);
}
__device__ __forceinline__ f32x4 f4zero() { f32x4 z = {0.f, 0.f, 0.f, 0.f}; return z; }

__device__ __forceinline__ bf16x8 cvt8(const float* __restrict__ p) {
  f32x4 x0 = *(const f32x4*)p;
  f32x4 x1 = *(const f32x4*)(p + 4);
  bf16x8 t;
  t[0] = (short)f2bf(x0[0]); t[1] = (short)f2bf(x0[1]);
  t[2] = (short)f2bf(x0[2]); t[3] = (short)f2bf(x0[3]);
  t[4] = (short)f2bf(x1[0]); t[5] = (short)f2bf(x1[1]);
  t[6] = (short)f2bf(x1[2]); t[7] = (short)f2bf(x1[3]);
  return t;
}

// ---------------------------------------------------------------------------
// Generic GEMM: Out[M,256] = act(A[M,256] @ W[256,256] + bias)
// ---------------------------------------------------------------------------
template<int ADT, int ACT, int ODT>
__global__ __launch_bounds__(256) void gemm_k256(
    const void* __restrict__ Av, const unsigned short* __restrict__ Wt,
    const float* __restrict__ bias, void* __restrict__ Outv, int M)
{
  const int m0  = (int)blockIdx.x * 64;
  const int tid = (int)threadIdx.x;
  const int w   = tid >> 6;
  const int l   = tid & 63;
  const int lr  = l & 15;
  const int g   = l >> 4;

  f32x4 acc[4][4];
#pragma unroll
  for (int a = 0; a < 4; ++a)
#pragma unroll
    for (int b = 0; b < 4; ++b) acc[a][b] = f4zero();

#pragma unroll
  for (int ks = 0; ks < 8; ++ks) {
    const int kb = ks * 32 + g * 8;
    bf16x8 af[4], bfr[4];
#pragma unroll
    for (int mf = 0; mf < 4; ++mf) {
      int row = m0 + mf * 16 + lr;
      if (row >= M) row = M - 1;
      if (ADT == 0)
        af[mf] = *(const bf16x8*)((const unsigned short*)Av + (size_t)row * 256 + kb);
      else
        af[mf] = cvt8((const float*)Av + (size_t)row * 256 + kb);
    }
#pragma unroll
    for (int nf = 0; nf < 4; ++nf) {
      const int col = w * 64 + nf * 16 + lr;
      bfr[nf] = *(const bf16x8*)(Wt + (size_t)col * 256 + kb);
    }
#pragma unroll
    for (int mf = 0; mf < 4; ++mf)
#pragma unroll
      for (int nf = 0; nf < 4; ++nf)
        acc[mf][nf] = MFMA(af[mf], bfr[nf], acc[mf][nf]);
  }

#pragma unroll
  for (int nf = 0; nf < 4; ++nf) {
    const int col = w * 64 + nf * 16 + lr;
    const float bs = bias[col];
#pragma unroll
    for (int mf = 0; mf < 4; ++mf) {
#pragma unroll
      for (int i = 0; i < 4; ++i) {
        const int row = m0 + mf * 16 + g * 4 + i;
        if (row < M) {
          float x = acc[mf][nf][i] + bs;
          if (ACT) x = sspf(x);
          if (ODT == 0)
            ((unsigned short*)Outv)[(size_t)row * 256 + col] = f2bf(x);
          else
            ((float*)Outv)[(size_t)row * 256 + col] = x;
        }
      }
    }
  }
}

// ---------------------------------------------------------------------------
// Counting sort by dst.
// ---------------------------------------------------------------------------
__global__ __launch_bounds__(256) void hist_dst(const int* __restrict__ eidx,
                                                int* __restrict__ cnt)
{
  const int e = (int)blockIdx.x * 256 + (int)threadIdx.x;
  atomicAdd(&cnt[eidx[N_EDGES + e]], 1);
}

__global__ __launch_bounds__(1024) void scan_cnt(const int* __restrict__ cnt,
                                                 int* __restrict__ cursor)
{
  __shared__ int part[1024];
  const int t = (int)threadIdx.x;
  const int base = t * 49;
  int s = 0;
#pragma unroll 7
  for (int j = 0; j < 49; ++j) {
    const int idx = base + j;
    if (idx < N_NODES) s += cnt[idx];
  }
  part[t] = s;
  __syncthreads();
  for (int off = 1; off < 1024; off <<= 1) {
    int v = 0;
    if (t >= off) v = part[t - off];
    __syncthreads();
    part[t] += v;
    __syncthreads();
  }
  int run = (t == 0) ? 0 : part[t - 1];
#pragma unroll 7
  for (int j = 0; j < 49; ++j) {
    const int idx = base + j;
    if (idx < N_NODES) { cursor[idx] = run; run += cnt[idx]; }
  }
}

// perm + Cf + srcs + dsts in sorted order
__global__ __launch_bounds__(256) void scatter_perm(
    const int* __restrict__ eidx, const float* __restrict__ ew,
    int* __restrict__ cursor, int* __restrict__ perm,
    float* __restrict__ Cf, int* __restrict__ srcs, int* __restrict__ dsts)
{
  const int e = (int)blockIdx.x * 256 + (int)threadIdx.x;
  const int d = eidx[N_EDGES + e];
  const int pos = atomicAdd(&cursor[d], 1);
  perm[pos] = e;
  Cf[pos]   = 0.5f * (__cosf(ew[e] * 0.31415926535897931f) + 1.0f);
  srcs[pos] = eidx[e];
  dsts[pos] = d;
}

// eattr_s[i][64] bf16 = eattr[perm[i]][k] (k<50), 0-padded. 8 lanes/edge.
__global__ __launch_bounds__(256) void prep_eattr(
    const float* __restrict__ ea, const int* __restrict__ perm,
    unsigned short* __restrict__ out)
{
  const int t = (int)blockIdx.x * 256 + (int)threadIdx.x;
  const int i = t >> 3, j = t & 7;
  const int p = perm[i];
  const float* ap = ea + (size_t)p * 50 + j * 8;
  bf16x8 v;
  if (j < 6) {
    f32x2 a0 = *(const f32x2*)(ap);
    f32x2 a1 = *(const f32x2*)(ap + 2);
    f32x2 a2 = *(const f32x2*)(ap + 4);
    f32x2 a3 = *(const f32x2*)(ap + 6);
    v[0] = (short)f2bf(a0[0]); v[1] = (short)f2bf(a0[1]);
    v[2] = (short)f2bf(a1[0]); v[3] = (short)f2bf(a1[1]);
    v[4] = (short)f2bf(a2[0]); v[5] = (short)f2bf(a2[1]);
    v[6] = (short)f2bf(a3[0]); v[7] = (short)f2bf(a3[1]);
  } else if (j == 6) {
    f32x2 a0 = *(const f32x2*)(ap);
    v[0] = (short)f2bf(a0[0]); v[1] = (short)f2bf(a0[1]);
    v[2] = 0; v[3] = 0; v[4] = 0; v[5] = 0; v[6] = 0; v[7] = 0;
  } else {
    v[0] = 0; v[1] = 0; v[2] = 0; v[3] = 0; v[4] = 0; v[5] = 0; v[6] = 0; v[7] = 0;
  }
  *(bf16x8*)(out + (size_t)i * 64 + j * 8) = v;
}

// ---------------------------------------------------------------------------
// FUSED edge pipeline over dst-SORTED edges. 64 edges/block, 512 thr (8
// waves, wave owns 32 cols). Wf never leaves LDS. Hoisted/decomposed LDS
// swizzle addressing: addr = lane_const + (ks*64 ^ P6) + mf*stride(imm).
// ---------------------------------------------------------------------------
__global__ __launch_bounds__(512, 8) void edge_fused512(
    const unsigned short* __restrict__ eattr_s,
    const float* __restrict__ Cf,
    const int* __restrict__ srcs, const int* __restrict__ dsts,
    const unsigned short* __restrict__ m1t, const float* __restrict__ m1b,
    const unsigned short* __restrict__ m2t, const float* __restrict__ m2b,
    const unsigned short* __restrict__ h1, float* __restrict__ agg)
{
  __shared__ unsigned short t_lds[64 * 256];  // 32 KiB; ea-tile, t, then Wf
  __shared__ float Cs[64];
  __shared__ int s_src[64];
  __shared__ int s_dst[65];
  unsigned short* ea_lds = t_lds;             // [64 rows][128B] alias (8 KiB)

  const int e0  = (int)blockIdx.x * 64;
  const int tid = (int)threadIdx.x;

  // ---- phase 0: stage sorted bf16 eattr rows into ea_lds (swizzled) + meta
  {
    const int r  = tid >> 3;                  // 0..63
    const int oc = tid & 7;                   // k-octet
    const bf16x8 v = *(const bf16x8*)(eattr_s + (size_t)(e0 + r) * 64 + oc * 8);
    const int byt = r * 128 + ((oc * 16) ^ ((r & 7) << 4));
    *(bf16x8*)((char*)ea_lds + byt) = v;
  }
  if (tid < 64) {
    Cs[tid]    = Cf[e0 + tid];
    s_src[tid] = srcs[e0 + tid];
    s_dst[tid] = dsts[e0 + tid];
  }
  if (tid == 64)
    s_dst[64] = (e0 + 64 < N_EDGES) ? dsts[e0 + 64] : -1;
  __syncthreads();

  const int w  = tid >> 6;                    // wave 0..7
  const int l  = tid & 63;
  const int lr = l & 15;
  const int g  = l >> 4;
  const int c0 = w * 32;                      // wave's column base

  // lane-constant swizzle bases (decomposition verified: XOR bits 4-6 never
  // collide with the row-stride term)
  const int P45  = (lr & 3) << 4;
  const int P6   = (lr & 4) << 4;
  const int alb1 = lr * 128 + ((g * 16) ^ P45);   // ea_lds A-read base
  const int alb2 = lr * 512 + ((g * 16) ^ P45);   // t_lds A-read base

  f32x4 acc[4][2];
#pragma unroll
  for (int a = 0; a < 4; ++a)
#pragma unroll
    for (int b = 0; b < 2; ++b) acc[a][b] = f4zero();

  // ---- stage 1: K=64 (k>=50 zero-padded both sides)
#pragma unroll
  for (int ks = 0; ks < 2; ++ks) {
    const int kb = ks * 32 + g * 8;
    const bf16x8 bfr0 = *(const bf16x8*)(m1t + (c0 + lr) * 64 + kb);
    const bf16x8 bfr1 = *(const bf16x8*)(m1t + (c0 + 16 + lr) * 64 + kb);
    const char* abase = (const char*)ea_lds + (alb1 + ((ks * 64) ^ P6));
#pragma unroll
    for (int mf = 0; mf < 4; ++mf) {
      const bf16x8 af = *(const bf16x8*)(abase + mf * 2048);
      __builtin_amdgcn_s_setprio(1);
      acc[mf][0] = MFMA(af, bfr0, acc[mf][0]);
      acc[mf][1] = MFMA(af, bfr1, acc[mf][1]);
      __builtin_amdgcn_s_setprio(0);
    }
  }
  __syncthreads();   // all ea_lds reads done before ep1 overwrites region

  // ---- epilogue 1: t = ssp(.) -> t_lds (addr: 8 computations / 32 writes)
#pragma unroll
  for (int nf = 0; nf < 2; ++nf) {
    const int col = c0 + nf * 16 + lr;
    const float bs = m1b[col];
    const int colb = col * 2;
#pragma unroll
    for (int i = 0; i < 4; ++i) {
      const int gi = g * 4 + i;
      char* wp = (char*)t_lds + (gi * 512 + (colb ^ ((gi & 7) << 4)));
#pragma unroll
      for (int mf = 0; mf < 4; ++mf) {
        const float x = sspf(acc[mf][nf][i] + bs);
        *(unsigned short*)(wp + mf * 8192) = f2bf(x);
      }
    }
  }
  __syncthreads();

  // ---- stage 2: K=256
#pragma unroll
  for (int a = 0; a < 4; ++a)
#pragma unroll
    for (int b = 0; b < 2; ++b) acc[a][b] = f4zero();

#pragma unroll
  for (int ks = 0; ks < 8; ++ks) {
    const int kb = ks * 32 + g * 8;
    const bf16x8 bfr0 = *(const bf16x8*)(m2t + (size_t)(c0 + lr) * 256 + kb);
    const bf16x8 bfr1 = *(const bf16x8*)(m2t + (size_t)(c0 + 16 + lr) * 256 + kb);
    const char* abase = (const char*)t_lds + (alb2 + ((ks * 64) ^ P6));
#pragma unroll
    for (int mf = 0; mf < 4; ++mf) {
      const bf16x8 af = *(const bf16x8*)(abase + mf * 8192);
      __builtin_amdgcn_s_setprio(1);
      acc[mf][0] = MFMA(af, bfr0, acc[mf][0]);
      acc[mf][1] = MFMA(af, bfr1, acc[mf][1]);
      __builtin_amdgcn_s_setprio(0);
    }
  }
  __syncthreads();   // stage-2 reads complete block-wide before overwrite

  // ---- epilogue 2: Wf = ssp(acc+b2)*C -> t_lds (same swizzle)
#pragma unroll
  for (int nf = 0; nf < 2; ++nf) {
    const int col = c0 + nf * 16 + lr;
    const float bs = m2b[col];
    const int colb = col * 2;
#pragma unroll
    for (int i = 0; i < 4; ++i) {
      const int gi = g * 4 + i;
      char* wp = (char*)t_lds + (gi * 512 + (colb ^ ((gi & 7) << 4)));
#pragma unroll
      for (int mf = 0; mf < 4; ++mf) {
        const float wf = sspf(acc[mf][nf][i] + bs) * Cs[mf * 16 + gi];
        *(unsigned short*)(wp + mf * 8192) = f2bf(wf);
      }
    }
  }
  __syncthreads();

  // ---- segmented reduce: quarter q2 owns rows 16q2..16q2+15; thread owns
  // col pair. h1 gather coalesced (2 waves x 256B per row). ~2 seg/quarter.
  {
    const int q2 = tid >> 7;                 // 0..3
    const int cp = (tid & 127) * 2;          // even column
    const int rb = q2 * 16;
    float s0 = 0.f, s1 = 0.f;
#pragma unroll
    for (int rr = 0; rr < 16; ++rr) {
      const int r = rb + rr;
      const int byt = r * 512 + ((cp * 2) ^ ((r & 7) << 4));
      const unsigned int wfp = *(const unsigned int*)((const char*)t_lds + byt);
      const unsigned int xjp =
          *(const unsigned int*)(h1 + (size_t)s_src[r] * 256 + cp);
      s0 += bf2f(wfp) * bf2f(xjp);
      s1 += bf2f(wfp >> 16) * bf2f(xjp >> 16);
      const int d = s_dst[r];
      if (rr == 15 || s_dst[r + 1] != d) {   // wave-uniform branch
        float* ap = agg + (size_t)d * 256 + cp;
        atomicAdd(ap, s0);
        atomicAdd(ap + 1, s1);
        s0 = 0.f; s1 = 0.f;
      }
    }
  }
}

// ---------------------------------------------------------------------------
// Transpose + downcast weights
// ---------------------------------------------------------------------------
__global__ __launch_bounds__(256) void prep_weights(
    const float* __restrict__ aw, const float* __restrict__ m1,
    const float* __restrict__ m2, const float* __restrict__ o1,
    const float* __restrict__ o2,
    unsigned short* __restrict__ awt, unsigned short* __restrict__ m1t,
    unsigned short* __restrict__ m2t, unsigned short* __restrict__ o1t,
    unsigned short* __restrict__ o2t)
{
  const int i = (int)blockIdx.x * 256 + (int)threadIdx.x;
  const int c = i >> 8, k = i & 255;
  const int src = k * 256 + c;
  awt[i] = f2bf(aw[src]);
  m2t[i] = f2bf(m2[src]);
  o1t[i] = f2bf(o1[src]);
  o2t[i] = f2bf(o2[src]);
  if (k < 64) m1t[c * 64 + k] = (k < 50) ? f2bf(m1[k * 256 + c]) : (unsigned short)0;
}

extern "C" void kernel_launch(void* const* d_in, const int* in_sizes, int n_in,
                              void* d_out, int out_size, void* d_ws, size_t ws_size,
                              hipStream_t stream)
{
  const float* h    = (const float*)d_in[0];
  const int*   eidx = (const int*)d_in[1];
  const float* ew   = (const float*)d_in[2];
  const float* ea   = (const float*)d_in[3];
  const float* awW  = (const float*)d_in[4];
  const float* awb  = (const float*)d_in[5];
  const float* m1W  = (const float*)d_in[6];
  const float* m1b  = (const float*)d_in[7];
  const float* m2W  = (const float*)d_in[8];
  const float* m2b  = (const float*)d_in[9];
  const float* o1W  = (const float*)d_in[10];
  const float* o1b  = (const float*)d_in[11];
  const float* o2W  = (const float*)d_in[12];
  const float* o2b  = (const float*)d_in[13];

  char* ws = (char*)d_ws;
  unsigned short* h1  = (unsigned short*)ws;                  // 25,600,000
  float*          agg = (float*)(ws + 25600000);              // 51,200,000
  char* wbase = ws + 25600000 + 51200000;                     // 76,800,000
  unsigned short* awt = (unsigned short*)wbase;               // 131072
  unsigned short* m2t = awt + 65536;                          // 131072
  unsigned short* o1t = m2t + 65536;                          // 131072
  unsigned short* o2t = o1t + 65536;                          // 131072
  unsigned short* m1t = o2t + 65536;                          // 32768
  char* p0 = wbase + 4 * 131072 + 32768;                      // 77,357,056
  int* cnt    = (int*)p0;                                     // 200,000
  int* cursor = cnt + N_NODES;                                // 200,000
  int* perm   = cursor + N_NODES;                             // 3,200,000
  char* p1 = p0 + 400000 + 3200000;                           // 80,957,056
  float* Cf   = (float*)p1;                                   // 3,200,000
  int*   srcs = (int*)(p1 + 3200000);                         // 3,200,000
  int*   dsts = (int*)(p1 + 6400000);                         // 3,200,000
  unsigned short* eattr_s = (unsigned short*)(p1 + 9600000);  // 102,400,000
  // total ~193 MB — proven available (R3/R4 ran this layout)

  hipMemsetAsync(agg, 0, (size_t)N_NODES * 256 * 4, stream);
  hipMemsetAsync(cnt, 0, (size_t)N_NODES * 4, stream);

  prep_weights<<<256, 256, 0, stream>>>(awW, m1W, m2W, o1W, o2W,
                                        awt, m1t, m2t, o1t, o2t);
  hist_dst<<<N_EDGES / 256, 256, 0, stream>>>(eidx, cnt);
  scan_cnt<<<1, 1024, 0, stream>>>(cnt, cursor);
  scatter_perm<<<N_EDGES / 256, 256, 0, stream>>>(eidx, ew, cursor, perm,
                                                  Cf, srcs, dsts);
  prep_eattr<<<N_EDGES * 8 / 256, 256, 0, stream>>>(ea, perm, eattr_s);

  // h1 = h @ aw_W + aw_b  (bf16 out) — needed by the fused edge kernel
  gemm_k256<1, 0, 0><<<(N_NODES + 63) / 64, 256, 0, stream>>>(h, awt, awb, h1, N_NODES);

  // fused edge MLP + CFConv aggregation (sorted order, Wf stays in LDS)
  edge_fused512<<<N_EDGES / 64, 512, 0, stream>>>(
      eattr_s, Cf, srcs, dsts, m1t, m1b, m2t, m2b, h1, agg);

  // o = ssp(agg @ o1_W + o1_b)   (into h1's buffer)
  gemm_k256<1, 1, 0><<<(N_NODES + 63) / 64, 256, 0, stream>>>(agg, o1t, o1b, h1, N_NODES);
  // out = o @ o2_W + o2_b
  gemm_k256<0, 0, 1><<<(N_NODES + 63) / 64, 256, 0, stream>>>(h1, o2t, o2b, d_out, N_NODES);
}

// Round 9
// 769.280 us; speedup vs baseline: 1.6956x; 1.2078x over previous
//
#include <hip/hip_runtime.h>

#define N_NODES 50000
#define N_EDGES 800000

typedef __attribute__((ext_vector_type(8))) short bf16x8;
typedef __attribute__((ext_vector_type(4))) float f32x4;
typedef __attribute__((ext_vector_type(2))) float f32x2;

__device__ __forceinline__ float bf2f(unsigned int u) {
  union { unsigned int u; float f; } c; c.u = (u & 0xffffu) << 16; return c.f;
}
// round-half-up: same half-ulp bound as RNE (differs only on exact ties)
__device__ __forceinline__ unsigned short f2bf(float f) {
  union { float f; unsigned int u; } c; c.f = f;
  return (unsigned short)((c.u + 0x8000u) >> 16);
}
__device__ __forceinline__ float sspf(float x) {
  return fmaxf(x, 0.0f) + __logf(1.0f + __expf(-fabsf(x))) - 0.69314718055994531f;
}
__device__ __forceinline__ f32x4 MFMA(bf16x8 a, bf16x8 b, f32x4 c) {
  return __builtin_amdgcn_mfma_f32_16x16x32_bf16(a, b, c, 0, 0, 0);
}
__device__ __forceinline__ f32x4 f4zero() { f32x4 z = {0.f, 0.f, 0.f, 0.f}; return z; }

__device__ __forceinline__ bf16x8 cvt8(const float* __restrict__ p) {
  f32x4 x0 = *(const f32x4*)p;
  f32x4 x1 = *(const f32x4*)(p + 4);
  bf16x8 t;
  t[0] = (short)f2bf(x0[0]); t[1] = (short)f2bf(x0[1]);
  t[2] = (short)f2bf(x0[2]); t[3] = (short)f2bf(x0[3]);
  t[4] = (short)f2bf(x1[0]); t[5] = (short)f2bf(x1[1]);
  t[6] = (short)f2bf(x1[2]); t[7] = (short)f2bf(x1[3]);
  return t;
}

// ---------------------------------------------------------------------------
// Node GEMM on the edge-kernel skeleton: Out[M,256] = act(A@W + bias).
// 512 thr / 8 waves, wave owns 32 cols. A staged once to swizzled bf16 LDS.
// ---------------------------------------------------------------------------
template<int ADT, int ACT, int ODT>
__global__ __launch_bounds__(512, 8) void gemm512(
    const void* __restrict__ Av, const unsigned short* __restrict__ Wt,
    const float* __restrict__ bias, void* __restrict__ Outv, int M)
{
  __shared__ unsigned short a_lds[64 * 256];  // 32 KiB, swizzled
  const int m0  = (int)blockIdx.x * 64;
  const int tid = (int)threadIdx.x;

  // ---- phase 0: stage A rows -> bf16 LDS (byte ^= (r&7)<<4 swizzle)
  {
    const int r   = tid >> 3;
    const int oc8 = tid & 7;                  // 32-col chunk
    int row = m0 + r;
    if (row >= M) row = M - 1;                // clamp; stores guarded
    if (ADT == 1) {
      const float* ap = (const float*)Av + (size_t)row * 256 + oc8 * 32;
#pragma unroll
      for (int q = 0; q < 4; ++q) {
        const bf16x8 v = cvt8(ap + q * 8);
        const int byt = r * 512 + ((oc8 * 64 + q * 16) ^ ((r & 7) << 4));
        *(bf16x8*)((char*)a_lds + byt) = v;
      }
    } else {
      const unsigned short* ap =
          (const unsigned short*)Av + (size_t)row * 256 + oc8 * 32;
#pragma unroll
      for (int q = 0; q < 4; ++q) {
        const bf16x8 v = *(const bf16x8*)(ap + q * 8);
        const int byt = r * 512 + ((oc8 * 64 + q * 16) ^ ((r & 7) << 4));
        *(bf16x8*)((char*)a_lds + byt) = v;
      }
    }
  }
  __syncthreads();

  const int w  = tid >> 6, l = tid & 63, lr = l & 15, g = l >> 4;
  const int c0 = w * 32;
  const int P45 = (lr & 3) << 4;
  const int P6  = (lr & 4) << 4;
  const int alb = lr * 512 + ((g * 16) ^ P45);

  f32x4 acc[4][2];
#pragma unroll
  for (int a = 0; a < 4; ++a)
#pragma unroll
    for (int b = 0; b < 2; ++b) acc[a][b] = f4zero();

#pragma unroll
  for (int ks = 0; ks < 8; ++ks) {
    const int kb = ks * 32 + g * 8;
    const bf16x8 bfr0 = *(const bf16x8*)(Wt + (size_t)(c0 + lr) * 256 + kb);
    const bf16x8 bfr1 = *(const bf16x8*)(Wt + (size_t)(c0 + 16 + lr) * 256 + kb);
    const char* abase = (const char*)a_lds + (alb + ((ks * 64) ^ P6));
#pragma unroll
    for (int mf = 0; mf < 4; ++mf) {
      const bf16x8 af = *(const bf16x8*)(abase + mf * 8192);
      __builtin_amdgcn_s_setprio(1);
      acc[mf][0] = MFMA(af, bfr0, acc[mf][0]);
      acc[mf][1] = MFMA(af, bfr1, acc[mf][1]);
      __builtin_amdgcn_s_setprio(0);
    }
  }

#pragma unroll
  for (int nf = 0; nf < 2; ++nf) {
    const int col = c0 + nf * 16 + lr;
    const float bs = bias[col];
#pragma unroll
    for (int mf = 0; mf < 4; ++mf) {
#pragma unroll
      for (int i = 0; i < 4; ++i) {
        const int row = m0 + mf * 16 + g * 4 + i;
        if (row < M) {
          float x = acc[mf][nf][i] + bs;
          if (ACT) x = sspf(x);
          if (ODT == 0)
            ((unsigned short*)Outv)[(size_t)row * 256 + col] = f2bf(x);
          else
            ((float*)Outv)[(size_t)row * 256 + col] = x;
        }
      }
    }
  }
}

// ---------------------------------------------------------------------------
// Counting sort by dst.
// ---------------------------------------------------------------------------
__global__ __launch_bounds__(256) void hist_dst(const int* __restrict__ eidx,
                                                int* __restrict__ cnt)
{
  const int e = (int)blockIdx.x * 256 + (int)threadIdx.x;
  atomicAdd(&cnt[eidx[N_EDGES + e]], 1);
}

__global__ __launch_bounds__(1024) void scan_cnt(const int* __restrict__ cnt,
                                                 int* __restrict__ cursor)
{
  __shared__ int part[1024];
  const int t = (int)threadIdx.x;
  const int base = t * 49;
  int s = 0;
#pragma unroll 7
  for (int j = 0; j < 49; ++j) {
    const int idx = base + j;
    if (idx < N_NODES) s += cnt[idx];
  }
  part[t] = s;
  __syncthreads();
  for (int off = 1; off < 1024; off <<= 1) {
    int v = 0;
    if (t >= off) v = part[t - off];
    __syncthreads();
    part[t] += v;
    __syncthreads();
  }
  int run = (t == 0) ? 0 : part[t - 1];
#pragma unroll 7
  for (int j = 0; j < 49; ++j) {
    const int idx = base + j;
    if (idx < N_NODES) { cursor[idx] = run; run += cnt[idx]; }
  }
}

// perm + Cf + srcs + dsts in sorted order
__global__ __launch_bounds__(256) void scatter_perm(
    const int* __restrict__ eidx, const float* __restrict__ ew,
    int* __restrict__ cursor, int* __restrict__ perm,
    float* __restrict__ Cf, int* __restrict__ srcs, int* __restrict__ dsts)
{
  const int e = (int)blockIdx.x * 256 + (int)threadIdx.x;
  const int d = eidx[N_EDGES + e];
  const int pos = atomicAdd(&cursor[d], 1);
  perm[pos] = e;
  Cf[pos]   = 0.5f * (__cosf(ew[e] * 0.31415926535897931f) + 1.0f);
  srcs[pos] = eidx[e];
  dsts[pos] = d;
}

// ---------------------------------------------------------------------------
// FUSED edge pipeline over dst-SORTED edges. 64 edges/block, 512 thr (8
// waves, wave owns 32 cols). Phase 0 gathers eattr[perm[e]] f32->bf16 into
// swizzled LDS directly (no prep_eattr pass). Wf never leaves LDS.
// ---------------------------------------------------------------------------
__global__ __launch_bounds__(512, 8) void edge_fused512(
    const float* __restrict__ eattr, const int* __restrict__ perm,
    const float* __restrict__ Cf,
    const int* __restrict__ srcs, const int* __restrict__ dsts,
    const unsigned short* __restrict__ m1t, const float* __restrict__ m1b,
    const unsigned short* __restrict__ m2t, const float* __restrict__ m2b,
    const unsigned short* __restrict__ h1, float* __restrict__ agg)
{
  __shared__ unsigned short t_lds[64 * 256];  // 32 KiB; ea-tile, t, then Wf
  __shared__ float Cs[64];
  __shared__ int s_src[64];
  __shared__ int s_dst[65];
  unsigned short* ea_lds = t_lds;             // [64 rows][128B] alias (8 KiB)

  const int e0  = (int)blockIdx.x * 64;
  const int tid = (int)threadIdx.x;

  // ---- phase 0: gather eattr[perm[e0+r]] -> bf16 ea_lds (swizzled) + meta
  {
    const int r  = tid >> 3;                  // 0..63
    const int oc = tid & 7;                   // k-octet
    const int p  = perm[e0 + r];              // L1-amortized (8 lanes/row)
    const float* ap = eattr + (size_t)p * 50 + oc * 8;   // 8B-aligned
    bf16x8 v;
    if (oc < 6) {
      f32x2 a0 = *(const f32x2*)(ap);
      f32x2 a1 = *(const f32x2*)(ap + 2);
      f32x2 a2 = *(const f32x2*)(ap + 4);
      f32x2 a3 = *(const f32x2*)(ap + 6);
      v[0] = (short)f2bf(a0[0]); v[1] = (short)f2bf(a0[1]);
      v[2] = (short)f2bf(a1[0]); v[3] = (short)f2bf(a1[1]);
      v[4] = (short)f2bf(a2[0]); v[5] = (short)f2bf(a2[1]);
      v[6] = (short)f2bf(a3[0]); v[7] = (short)f2bf(a3[1]);
    } else if (oc == 6) {
      f32x2 a0 = *(const f32x2*)(ap);
      v[0] = (short)f2bf(a0[0]); v[1] = (short)f2bf(a0[1]);
      v[2] = 0; v[3] = 0; v[4] = 0; v[5] = 0; v[6] = 0; v[7] = 0;
    } else {
      v[0] = 0; v[1] = 0; v[2] = 0; v[3] = 0; v[4] = 0; v[5] = 0; v[6] = 0; v[7] = 0;
    }
    const int byt = r * 128 + ((oc * 16) ^ ((r & 7) << 4));
    *(bf16x8*)((char*)ea_lds + byt) = v;
  }
  if (tid < 64) {
    Cs[tid]    = Cf[e0 + tid];
    s_src[tid] = srcs[e0 + tid];
    s_dst[tid] = dsts[e0 + tid];
  }
  if (tid == 64)
    s_dst[64] = (e0 + 64 < N_EDGES) ? dsts[e0 + 64] : -1;
  __syncthreads();

  const int w  = tid >> 6;                    // wave 0..7
  const int l  = tid & 63;
  const int lr = l & 15;
  const int g  = l >> 4;
  const int c0 = w * 32;                      // wave's column base

  // lane-constant swizzle bases (XOR bits 4-6 disjoint from row stride)
  const int P45  = (lr & 3) << 4;
  const int P6   = (lr & 4) << 4;
  const int alb1 = lr * 128 + ((g * 16) ^ P45);   // ea_lds A-read base
  const int alb2 = lr * 512 + ((g * 16) ^ P45);   // t_lds A-read base

  f32x4 acc[4][2];
#pragma unroll
  for (int a = 0; a < 4; ++a)
#pragma unroll
    for (int b = 0; b < 2; ++b) acc[a][b] = f4zero();

  // ---- stage 1: K=64 (k>=50 zero-padded both sides)
#pragma unroll
  for (int ks = 0; ks < 2; ++ks) {
    const int kb = ks * 32 + g * 8;
    const bf16x8 bfr0 = *(const bf16x8*)(m1t + (c0 + lr) * 64 + kb);
    const bf16x8 bfr1 = *(const bf16x8*)(m1t + (c0 + 16 + lr) * 64 + kb);
    const char* abase = (const char*)ea_lds + (alb1 + ((ks * 64) ^ P6));
#pragma unroll
    for (int mf = 0; mf < 4; ++mf) {
      const bf16x8 af = *(const bf16x8*)(abase + mf * 2048);
      __builtin_amdgcn_s_setprio(1);
      acc[mf][0] = MFMA(af, bfr0, acc[mf][0]);
      acc[mf][1] = MFMA(af, bfr1, acc[mf][1]);
      __builtin_amdgcn_s_setprio(0);
    }
  }
  __syncthreads();   // all ea_lds reads done before ep1 overwrites region

  // ---- epilogue 1: t = ssp(.) -> t_lds
#pragma unroll
  for (int nf = 0; nf < 2; ++nf) {
    const int col = c0 + nf * 16 + lr;
    const float bs = m1b[col];
    const int colb = col * 2;
#pragma unroll
    for (int i = 0; i < 4; ++i) {
      const int gi = g * 4 + i;
      char* wp = (char*)t_lds + (gi * 512 + (colb ^ ((gi & 7) << 4)));
#pragma unroll
      for (int mf = 0; mf < 4; ++mf) {
        const float x = sspf(acc[mf][nf][i] + bs);
        *(unsigned short*)(wp + mf * 8192) = f2bf(x);
      }
    }
  }
  __syncthreads();

  // ---- stage 2: K=256
#pragma unroll
  for (int a = 0; a < 4; ++a)
#pragma unroll
    for (int b = 0; b < 2; ++b) acc[a][b] = f4zero();

#pragma unroll
  for (int ks = 0; ks < 8; ++ks) {
    const int kb = ks * 32 + g * 8;
    const bf16x8 bfr0 = *(const bf16x8*)(m2t + (size_t)(c0 + lr) * 256 + kb);
    const bf16x8 bfr1 = *(const bf16x8*)(m2t + (size_t)(c0 + 16 + lr) * 256 + kb);
    const char* abase = (const char*)t_lds + (alb2 + ((ks * 64) ^ P6));
#pragma unroll
    for (int mf = 0; mf < 4; ++mf) {
      const bf16x8 af = *(const bf16x8*)(abase + mf * 8192);
      __builtin_amdgcn_s_setprio(1);
      acc[mf][0] = MFMA(af, bfr0, acc[mf][0]);
      acc[mf][1] = MFMA(af, bfr1, acc[mf][1]);
      __builtin_amdgcn_s_setprio(0);
    }
  }
  __syncthreads();   // stage-2 reads complete block-wide before overwrite

  // ---- epilogue 2: Wf = ssp(acc+b2)*C -> t_lds (same swizzle)
#pragma unroll
  for (int nf = 0; nf < 2; ++nf) {
    const int col = c0 + nf * 16 + lr;
    const float bs = m2b[col];
    const int colb = col * 2;
#pragma unroll
    for (int i = 0; i < 4; ++i) {
      const int gi = g * 4 + i;
      char* wp = (char*)t_lds + (gi * 512 + (colb ^ ((gi & 7) << 4)));
#pragma unroll
      for (int mf = 0; mf < 4; ++mf) {
        const float wf = sspf(acc[mf][nf][i] + bs) * Cs[mf * 16 + gi];
        *(unsigned short*)(wp + mf * 8192) = f2bf(wf);
      }
    }
  }
  __syncthreads();

  // ---- segmented reduce: quarter q2 owns rows 16q2..16q2+15; thread owns
  // col pair. h1 gather coalesced (2 waves x 256B per row).
  {
    const int q2 = tid >> 7;                 // 0..3
    const int cp = (tid & 127) * 2;          // even column
    const int rb = q2 * 16;
    float s0 = 0.f, s1 = 0.f;
#pragma unroll
    for (int rr = 0; rr < 16; ++rr) {
      const int r = rb + rr;
      const int byt = r * 512 + ((cp * 2) ^ ((r & 7) << 4));
      const unsigned int wfp = *(const unsigned int*)((const char*)t_lds + byt);
      const unsigned int xjp =
          *(const unsigned int*)(h1 + (size_t)s_src[r] * 256 + cp);
      s0 += bf2f(wfp) * bf2f(xjp);
      s1 += bf2f(wfp >> 16) * bf2f(xjp >> 16);
      const int d = s_dst[r];
      if (rr == 15 || s_dst[r + 1] != d) {   // wave-uniform branch
        float* ap = agg + (size_t)d * 256 + cp;
        atomicAdd(ap, s0);
        atomicAdd(ap + 1, s1);
        s0 = 0.f; s1 = 0.f;
      }
    }
  }
}

// ---------------------------------------------------------------------------
// Transpose + downcast weights
// ---------------------------------------------------------------------------
__global__ __launch_bounds__(256) void prep_weights(
    const float* __restrict__ aw, const float* __restrict__ m1,
    const float* __restrict__ m2, const float* __restrict__ o1,
    const float* __restrict__ o2,
    unsigned short* __restrict__ awt, unsigned short* __restrict__ m1t,
    unsigned short* __restrict__ m2t, unsigned short* __restrict__ o1t,
    unsigned short* __restrict__ o2t)
{
  const int i = (int)blockIdx.x * 256 + (int)threadIdx.x;
  const int c = i >> 8, k = i & 255;
  const int src = k * 256 + c;
  awt[i] = f2bf(aw[src]);
  m2t[i] = f2bf(m2[src]);
  o1t[i] = f2bf(o1[src]);
  o2t[i] = f2bf(o2[src]);
  if (k < 64) m1t[c * 64 + k] = (k < 50) ? f2bf(m1[k * 256 + c]) : (unsigned short)0;
}

extern "C" void kernel_launch(void* const* d_in, const int* in_sizes, int n_in,
                              void* d_out, int out_size, void* d_ws, size_t ws_size,
                              hipStream_t stream)
{
  const float* h    = (const float*)d_in[0];
  const int*   eidx = (const int*)d_in[1];
  const float* ew   = (const float*)d_in[2];
  const float* ea   = (const float*)d_in[3];
  const float* awW  = (const float*)d_in[4];
  const float* awb  = (const float*)d_in[5];
  const float* m1W  = (const float*)d_in[6];
  const float* m1b  = (const float*)d_in[7];
  const float* m2W  = (const float*)d_in[8];
  const float* m2b  = (const float*)d_in[9];
  const float* o1W  = (const float*)d_in[10];
  const float* o1b  = (const float*)d_in[11];
  const float* o2W  = (const float*)d_in[12];
  const float* o2b  = (const float*)d_in[13];

  char* ws = (char*)d_ws;
  unsigned short* h1  = (unsigned short*)ws;                  // 25,600,000
  float*          agg = (float*)(ws + 25600000);              // 51,200,000
  char* wbase = ws + 25600000 + 51200000;                     // 76,800,000
  unsigned short* awt = (unsigned short*)wbase;               // 131072
  unsigned short* m2t = awt + 65536;                          // 131072
  unsigned short* o1t = m2t + 65536;                          // 131072
  unsigned short* o2t = o1t + 65536;                          // 131072
  unsigned short* m1t = o2t + 65536;                          // 32768
  char* p0 = wbase + 4 * 131072 + 32768;                      // 77,357,056
  int* cnt    = (int*)p0;                                     // 200,000
  int* cursor = cnt + N_NODES;                                // 200,000
  int* perm   = cursor + N_NODES;                             // 3,200,000
  char* p1 = p0 + 400000 + 3200000;                           // 80,957,056
  float* Cf   = (float*)p1;                                   // 3,200,000
  int*   srcs = (int*)(p1 + 3200000);                         // 3,200,000
  int*   dsts = (int*)(p1 + 6400000);                         // 3,200,000
  // total ~90.6 MB

  hipMemsetAsync(agg, 0, (size_t)N_NODES * 256 * 4, stream);
  hipMemsetAsync(cnt, 0, (size_t)N_NODES * 4, stream);

  prep_weights<<<256, 256, 0, stream>>>(awW, m1W, m2W, o1W, o2W,
                                        awt, m1t, m2t, o1t, o2t);
  hist_dst<<<N_EDGES / 256, 256, 0, stream>>>(eidx, cnt);
  scan_cnt<<<1, 1024, 0, stream>>>(cnt, cursor);
  scatter_perm<<<N_EDGES / 256, 256, 0, stream>>>(eidx, ew, cursor, perm,
                                                  Cf, srcs, dsts);

  // h1 = h @ aw_W + aw_b  (bf16 out) — needed by the fused edge kernel
  gemm512<1, 0, 0><<<(N_NODES + 63) / 64, 512, 0, stream>>>(h, awt, awb, h1, N_NODES);

  // fused edge MLP + CFConv aggregation (sorted order, direct eattr gather)
  edge_fused512<<<N_EDGES / 64, 512, 0, stream>>>(
      ea, perm, Cf, srcs, dsts, m1t, m1b, m2t, m2b, h1, agg);

  // o = ssp(agg @ o1_W + o1_b)   (into h1's buffer)
  gemm512<1, 1, 0><<<(N_NODES + 63) / 64, 512, 0, stream>>>(agg, o1t, o1b, h1, N_NODES);
  // out = o @ o2_W + o2_b
  gemm512<0, 0, 1><<<(N_NODES + 63) / 64, 512, 0, stream>>>(h1, o2t, o2b, d_out, N_NODES);
}

// Round 10
// 698.631 us; speedup vs baseline: 1.8670x; 1.1011x over previous
//
#include <hip/hip_runtime.h>

#define N_NODES 50000
#define N_EDGES 800000

typedef __attribute__((ext_vector_type(8))) short bf16x8;
typedef __attribute__((ext_vector_type(4))) float f32x4;
typedef __attribute__((ext_vector_type(2))) float f32x2;
typedef __attribute__((ext_vector_type(4))) unsigned int u32x4;

__device__ __forceinline__ float bf2f(unsigned int u) {
  union { unsigned int u; float f; } c; c.u = (u & 0xffffu) << 16; return c.f;
}
// round-half-up scalar fallback (prep_weights / guarded stores)
__device__ __forceinline__ unsigned short f2bf(float f) {
  union { float f; unsigned int u; } c; c.f = f;
  return (unsigned short)((c.u + 0x8000u) >> 16);
}
// RNE packed f32x2 -> 2xbf16 in one VALU op (gfx950-verified instruction)
__device__ __forceinline__ unsigned int pk_bf16(float lo, float hi) {
  unsigned int r;
  asm("v_cvt_pk_bf16_f32 %0, %1, %2" : "=v"(r) : "v"(lo), "v"(hi));
  return r;
}

#if __has_builtin(__builtin_amdgcn_exp2f) && __has_builtin(__builtin_amdgcn_logf)
// ssp(x) = max(x,0) + ln2*log2(1 + 2^(-log2e*|x|)) - ln2   (~7 VALU)
__device__ __forceinline__ float sspf(float x) {
  const float e = __builtin_amdgcn_exp2f(fabsf(x) * -1.44269504088896f);
  const float l = __builtin_amdgcn_logf(1.0f + e);
  return fmaf(0.69314718055994531f, l, fmaxf(x, 0.0f) - 0.69314718055994531f);
}
#else
__device__ __forceinline__ float sspf(float x) {
  return fmaxf(x, 0.0f) + __logf(1.0f + __expf(-fabsf(x))) - 0.69314718055994531f;
}
#endif

__device__ __forceinline__ f32x4 MFMA(bf16x8 a, bf16x8 b, f32x4 c) {
  return __builtin_amdgcn_mfma_f32_16x16x32_bf16(a, b, c, 0, 0, 0);
}
__device__ __forceinline__ f32x4 f4bcast(float v) {
  f32x4 z = {v, v, v, v}; return z;
}

// 8 contiguous f32 -> bf16x8 via 4 cvt_pk
__device__ __forceinline__ bf16x8 cvt8pk(const float* __restrict__ p) {
  f32x4 x0 = *(const f32x4*)p;
  f32x4 x1 = *(const f32x4*)(p + 4);
  union { u32x4 u; bf16x8 v; } r;
  r.u[0] = pk_bf16(x0[0], x0[1]);
  r.u[1] = pk_bf16(x0[2], x0[3]);
  r.u[2] = pk_bf16(x1[0], x1[1]);
  r.u[3] = pk_bf16(x1[2], x1[3]);
  return r.v;
}

// ---------------------------------------------------------------------------
// Node GEMM: Out[M,256] = act(A@W + bias). 512 thr / 8 waves, wave owns 32
// cols. A staged once to swizzled bf16 LDS. Bias pre-loaded into acc.
// ---------------------------------------------------------------------------
template<int ADT, int ACT, int ODT>
__global__ __launch_bounds__(512, 8) void gemm512(
    const void* __restrict__ Av, const unsigned short* __restrict__ Wt,
    const float* __restrict__ bias, void* __restrict__ Outv, int M)
{
  __shared__ unsigned short a_lds[64 * 256];  // 32 KiB, swizzled
  const int m0  = (int)blockIdx.x * 64;
  const int tid = (int)threadIdx.x;

  // ---- phase 0: stage A rows -> bf16 LDS (byte ^= (r&7)<<4 swizzle)
  {
    const int r   = tid >> 3;
    const int oc8 = tid & 7;                  // 32-col chunk
    int row = m0 + r;
    if (row >= M) row = M - 1;                // clamp; stores guarded
    if (ADT == 1) {
      const float* ap = (const float*)Av + (size_t)row * 256 + oc8 * 32;
#pragma unroll
      for (int q = 0; q < 4; ++q) {
        const bf16x8 v = cvt8pk(ap + q * 8);
        const int byt = r * 512 + ((oc8 * 64 + q * 16) ^ ((r & 7) << 4));
        *(bf16x8*)((char*)a_lds + byt) = v;
      }
    } else {
      const unsigned short* ap =
          (const unsigned short*)Av + (size_t)row * 256 + oc8 * 32;
#pragma unroll
      for (int q = 0; q < 4; ++q) {
        const bf16x8 v = *(const bf16x8*)(ap + q * 8);
        const int byt = r * 512 + ((oc8 * 64 + q * 16) ^ ((r & 7) << 4));
        *(bf16x8*)((char*)a_lds + byt) = v;
      }
    }
  }
  __syncthreads();

  const int w  = tid >> 6, l = tid & 63, lr = l & 15, g = l >> 4;
  const int c0 = w * 32;
  const int P45 = (lr & 3) << 4;
  const int P6  = (lr & 4) << 4;
  const int alb = lr * 512 + ((g * 16) ^ P45);

  const float bs0 = bias[c0 + lr];
  const float bs1 = bias[c0 + 16 + lr];
  f32x4 acc[4][2];
#pragma unroll
  for (int a = 0; a < 4; ++a) {
    acc[a][0] = f4bcast(bs0);
    acc[a][1] = f4bcast(bs1);
  }

#pragma unroll
  for (int ks = 0; ks < 8; ++ks) {
    const int kb = ks * 32 + g * 8;
    const bf16x8 bfr0 = *(const bf16x8*)(Wt + (size_t)(c0 + lr) * 256 + kb);
    const bf16x8 bfr1 = *(const bf16x8*)(Wt + (size_t)(c0 + 16 + lr) * 256 + kb);
    const char* abase = (const char*)a_lds + (alb + ((ks * 64) ^ P6));
#pragma unroll
    for (int mf = 0; mf < 4; ++mf) {
      const bf16x8 af = *(const bf16x8*)(abase + mf * 8192);
      __builtin_amdgcn_s_setprio(1);
      acc[mf][0] = MFMA(af, bfr0, acc[mf][0]);
      acc[mf][1] = MFMA(af, bfr1, acc[mf][1]);
      __builtin_amdgcn_s_setprio(0);
    }
  }

#pragma unroll
  for (int nf = 0; nf < 2; ++nf) {
    const int col = c0 + nf * 16 + lr;
#pragma unroll
    for (int mf = 0; mf < 4; ++mf) {
#pragma unroll
      for (int i = 0; i < 4; ++i) {
        const int row = m0 + mf * 16 + g * 4 + i;
        if (row < M) {
          float x = acc[mf][nf][i];
          if (ACT) x = sspf(x);
          if (ODT == 0)
            ((unsigned short*)Outv)[(size_t)row * 256 + col] = f2bf(x);
          else
            ((float*)Outv)[(size_t)row * 256 + col] = x;
        }
      }
    }
  }
}

// ---------------------------------------------------------------------------
// Counting sort by dst.
// ---------------------------------------------------------------------------
__global__ __launch_bounds__(256) void hist_dst(const int* __restrict__ eidx,
                                                int* __restrict__ cnt)
{
  const int e = (int)blockIdx.x * 256 + (int)threadIdx.x;
  atomicAdd(&cnt[eidx[N_EDGES + e]], 1);
}

__global__ __launch_bounds__(1024) void scan_cnt(const int* __restrict__ cnt,
                                                 int* __restrict__ cursor)
{
  __shared__ int part[1024];
  const int t = (int)threadIdx.x;
  const int base = t * 49;
  int s = 0;
#pragma unroll 7
  for (int j = 0; j < 49; ++j) {
    const int idx = base + j;
    if (idx < N_NODES) s += cnt[idx];
  }
  part[t] = s;
  __syncthreads();
  for (int off = 1; off < 1024; off <<= 1) {
    int v = 0;
    if (t >= off) v = part[t - off];
    __syncthreads();
    part[t] += v;
    __syncthreads();
  }
  int run = (t == 0) ? 0 : part[t - 1];
#pragma unroll 7
  for (int j = 0; j < 49; ++j) {
    const int idx = base + j;
    if (idx < N_NODES) { cursor[idx] = run; run += cnt[idx]; }
  }
}

// perm + Cf + srcs + dsts in sorted order
__global__ __launch_bounds__(256) void scatter_perm(
    const int* __restrict__ eidx, const float* __restrict__ ew,
    int* __restrict__ cursor, int* __restrict__ perm,
    float* __restrict__ Cf, int* __restrict__ srcs, int* __restrict__ dsts)
{
  const int e = (int)blockIdx.x * 256 + (int)threadIdx.x;
  const int d = eidx[N_EDGES + e];
  const int pos = atomicAdd(&cursor[d], 1);
  perm[pos] = e;
  Cf[pos]   = 0.5f * (__cosf(ew[e] * 0.31415926535897931f) + 1.0f);
  srcs[pos] = eidx[e];
  dsts[pos] = d;
}

// ---------------------------------------------------------------------------
// FUSED edge pipeline over dst-SORTED edges. 64 edges/block, 512 thr (8
// waves, wave owns 32 cols). Direct eattr[perm] gather -> swizzled LDS.
// Bias in acc; cvt_pk epilogues; Wf never leaves LDS.
// ---------------------------------------------------------------------------
__global__ __launch_bounds__(512, 8) void edge_fused512(
    const float* __restrict__ eattr, const int* __restrict__ perm,
    const float* __restrict__ Cf,
    const int* __restrict__ srcs, const int* __restrict__ dsts,
    const unsigned short* __restrict__ m1t, const float* __restrict__ m1b,
    const unsigned short* __restrict__ m2t, const float* __restrict__ m2b,
    const unsigned short* __restrict__ h1, float* __restrict__ agg)
{
  __shared__ unsigned short t_lds[64 * 256];  // 32 KiB; ea-tile, t, then Wf
  __shared__ float Cs[64];
  __shared__ int s_src[64];
  __shared__ int s_dst[65];
  unsigned short* ea_lds = t_lds;             // [64 rows][128B] alias (8 KiB)

  const int e0  = (int)blockIdx.x * 64;
  const int tid = (int)threadIdx.x;

  // ---- phase 0: gather eattr[perm[e0+r]] -> bf16 ea_lds (swizzled) + meta
  {
    const int r  = tid >> 3;                  // 0..63
    const int oc = tid & 7;                   // k-octet
    const int p  = perm[e0 + r];              // L1-amortized (8 lanes/row)
    const float* ap = eattr + (size_t)p * 50 + oc * 8;   // 8B-aligned
    union { u32x4 u; bf16x8 v; } t;
    if (oc < 6) {
      f32x2 a0 = *(const f32x2*)(ap);
      f32x2 a1 = *(const f32x2*)(ap + 2);
      f32x2 a2 = *(const f32x2*)(ap + 4);
      f32x2 a3 = *(const f32x2*)(ap + 6);
      t.u[0] = pk_bf16(a0[0], a0[1]);
      t.u[1] = pk_bf16(a1[0], a1[1]);
      t.u[2] = pk_bf16(a2[0], a2[1]);
      t.u[3] = pk_bf16(a3[0], a3[1]);
    } else if (oc == 6) {
      f32x2 a0 = *(const f32x2*)(ap);
      t.u[0] = pk_bf16(a0[0], a0[1]);
      t.u[1] = 0; t.u[2] = 0; t.u[3] = 0;
    } else {
      t.u[0] = 0; t.u[1] = 0; t.u[2] = 0; t.u[3] = 0;
    }
    const int byt = r * 128 + ((oc * 16) ^ ((r & 7) << 4));
    *(bf16x8*)((char*)ea_lds + byt) = t.v;
  }
  if (tid < 64) {
    Cs[tid]    = Cf[e0 + tid];
    s_src[tid] = srcs[e0 + tid];
    s_dst[tid] = dsts[e0 + tid];
  }
  if (tid == 64)
    s_dst[64] = (e0 + 64 < N_EDGES) ? dsts[e0 + 64] : -1;
  __syncthreads();

  const int w  = tid >> 6;                    // wave 0..7
  const int l  = tid & 63;
  const int lr = l & 15;
  const int g  = l >> 4;
  const int c0 = w * 32;                      // wave's column base

  // lane-constant swizzle bases (XOR bits 4-6 disjoint from row stride)
  const int P45  = (lr & 3) << 4;
  const int P6   = (lr & 4) << 4;
  const int alb1 = lr * 128 + ((g * 16) ^ P45);   // ea_lds A-read base
  const int alb2 = lr * 512 + ((g * 16) ^ P45);   // t_lds A-read base

  const float b10 = m1b[c0 + lr];
  const float b11 = m1b[c0 + 16 + lr];
  f32x4 acc[4][2];
#pragma unroll
  for (int a = 0; a < 4; ++a) {
    acc[a][0] = f4bcast(b10);
    acc[a][1] = f4bcast(b11);
  }

  // ---- stage 1: K=64 (k>=50 zero-padded both sides)
#pragma unroll
  for (int ks = 0; ks < 2; ++ks) {
    const int kb = ks * 32 + g * 8;
    const bf16x8 bfr0 = *(const bf16x8*)(m1t + (c0 + lr) * 64 + kb);
    const bf16x8 bfr1 = *(const bf16x8*)(m1t + (c0 + 16 + lr) * 64 + kb);
    const char* abase = (const char*)ea_lds + (alb1 + ((ks * 64) ^ P6));
#pragma unroll
    for (int mf = 0; mf < 4; ++mf) {
      const bf16x8 af = *(const bf16x8*)(abase + mf * 2048);
      __builtin_amdgcn_s_setprio(1);
      acc[mf][0] = MFMA(af, bfr0, acc[mf][0]);
      acc[mf][1] = MFMA(af, bfr1, acc[mf][1]);
      __builtin_amdgcn_s_setprio(0);
    }
  }
  __syncthreads();   // all ea_lds reads done before ep1 overwrites region

  // ---- epilogue 1: t = ssp(.) -> t_lds (cvt_pk pairs across mf)
#pragma unroll
  for (int nf = 0; nf < 2; ++nf) {
    const int colb = (c0 + nf * 16 + lr) * 2;
#pragma unroll
    for (int i = 0; i < 4; ++i) {
      const int gi = g * 4 + i;
      char* wp = (char*)t_lds + (gi * 512 + (colb ^ ((gi & 7) << 4)));
      const float v0 = sspf(acc[0][nf][i]);
      const float v1 = sspf(acc[1][nf][i]);
      const float v2 = sspf(acc[2][nf][i]);
      const float v3 = sspf(acc[3][nf][i]);
      const unsigned int p01 = pk_bf16(v0, v1);
      const unsigned int p23 = pk_bf16(v2, v3);
      *(unsigned short*)(wp)         = (unsigned short)p01;
      *(unsigned short*)(wp + 8192)  = (unsigned short)(p01 >> 16);
      *(unsigned short*)(wp + 16384) = (unsigned short)p23;
      *(unsigned short*)(wp + 24576) = (unsigned short)(p23 >> 16);
    }
  }
  __syncthreads();

  // ---- stage 2: K=256
  const float b20 = m2b[c0 + lr];
  const float b21 = m2b[c0 + 16 + lr];
#pragma unroll
  for (int a = 0; a < 4; ++a) {
    acc[a][0] = f4bcast(b20);
    acc[a][1] = f4bcast(b21);
  }

#pragma unroll
  for (int ks = 0; ks < 8; ++ks) {
    const int kb = ks * 32 + g * 8;
    const bf16x8 bfr0 = *(const bf16x8*)(m2t + (size_t)(c0 + lr) * 256 + kb);
    const bf16x8 bfr1 = *(const bf16x8*)(m2t + (size_t)(c0 + 16 + lr) * 256 + kb);
    const char* abase = (const char*)t_lds + (alb2 + ((ks * 64) ^ P6));
#pragma unroll
    for (int mf = 0; mf < 4; ++mf) {
      const bf16x8 af = *(const bf16x8*)(abase + mf * 8192);
      __builtin_amdgcn_s_setprio(1);
      acc[mf][0] = MFMA(af, bfr0, acc[mf][0]);
      acc[mf][1] = MFMA(af, bfr1, acc[mf][1]);
      __builtin_amdgcn_s_setprio(0);
    }
  }
  __syncthreads();   // stage-2 reads complete block-wide before overwrite

  // ---- epilogue 2: Wf = ssp(acc)*C -> t_lds (same swizzle, cvt_pk)
#pragma unroll
  for (int nf = 0; nf < 2; ++nf) {
    const int colb = (c0 + nf * 16 + lr) * 2;
#pragma unroll
    for (int i = 0; i < 4; ++i) {
      const int gi = g * 4 + i;
      char* wp = (char*)t_lds + (gi * 512 + (colb ^ ((gi & 7) << 4)));
      const float v0 = sspf(acc[0][nf][i]) * Cs[gi];
      const float v1 = sspf(acc[1][nf][i]) * Cs[16 + gi];
      const float v2 = sspf(acc[2][nf][i]) * Cs[32 + gi];
      const float v3 = sspf(acc[3][nf][i]) * Cs[48 + gi];
      const unsigned int p01 = pk_bf16(v0, v1);
      const unsigned int p23 = pk_bf16(v2, v3);
      *(unsigned short*)(wp)         = (unsigned short)p01;
      *(unsigned short*)(wp + 8192)  = (unsigned short)(p01 >> 16);
      *(unsigned short*)(wp + 16384) = (unsigned short)p23;
      *(unsigned short*)(wp + 24576) = (unsigned short)(p23 >> 16);
    }
  }
  __syncthreads();

  // ---- segmented reduce: quarter q2 owns rows 16q2..16q2+15; thread owns
  // col pair. h1 gather coalesced (2 waves x 256B per row).
  {
    const int q2 = tid >> 7;                 // 0..3
    const int cp = (tid & 127) * 2;          // even column
    const int rb = q2 * 16;
    float s0 = 0.f, s1 = 0.f;
#pragma unroll
    for (int rr = 0; rr < 16; ++rr) {
      const int r = rb + rr;
      const int byt = r * 512 + ((cp * 2) ^ ((r & 7) << 4));
      const unsigned int wfp = *(const unsigned int*)((const char*)t_lds + byt);
      const unsigned int xjp =
          *(const unsigned int*)(h1 + (size_t)s_src[r] * 256 + cp);
      s0 += bf2f(wfp) * bf2f(xjp);
      s1 += bf2f(wfp >> 16) * bf2f(xjp >> 16);
      const int d = s_dst[r];
      if (rr == 15 || s_dst[r + 1] != d) {   // wave-uniform branch
        float* ap = agg + (size_t)d * 256 + cp;
        atomicAdd(ap, s0);
        atomicAdd(ap + 1, s1);
        s0 = 0.f; s1 = 0.f;
      }
    }
  }
}

// ---------------------------------------------------------------------------
// Transpose + downcast weights
// ---------------------------------------------------------------------------
__global__ __launch_bounds__(256) void prep_weights(
    const float* __restrict__ aw, const float* __restrict__ m1,
    const float* __restrict__ m2, const float* __restrict__ o1,
    const float* __restrict__ o2,
    unsigned short* __restrict__ awt, unsigned short* __restrict__ m1t,
    unsigned short* __restrict__ m2t, unsigned short* __restrict__ o1t,
    unsigned short* __restrict__ o2t)
{
  const int i = (int)blockIdx.x * 256 + (int)threadIdx.x;
  const int c = i >> 8, k = i & 255;
  const int src = k * 256 + c;
  awt[i] = f2bf(aw[src]);
  m2t[i] = f2bf(m2[src]);
  o1t[i] = f2bf(o1[src]);
  o2t[i] = f2bf(o2[src]);
  if (k < 64) m1t[c * 64 + k] = (k < 50) ? f2bf(m1[k * 256 + c]) : (unsigned short)0;
}

extern "C" void kernel_launch(void* const* d_in, const int* in_sizes, int n_in,
                              void* d_out, int out_size, void* d_ws, size_t ws_size,
                              hipStream_t stream)
{
  const float* h    = (const float*)d_in[0];
  const int*   eidx = (const int*)d_in[1];
  const float* ew   = (const float*)d_in[2];
  const float* ea   = (const float*)d_in[3];
  const float* awW  = (const float*)d_in[4];
  const float* awb  = (const float*)d_in[5];
  const float* m1W  = (const float*)d_in[6];
  const float* m1b  = (const float*)d_in[7];
  const float* m2W  = (const float*)d_in[8];
  const float* m2b  = (const float*)d_in[9];
  const float* o1W  = (const float*)d_in[10];
  const float* o1b  = (const float*)d_in[11];
  const float* o2W  = (const float*)d_in[12];
  const float* o2b  = (const float*)d_in[13];

  char* ws = (char*)d_ws;
  unsigned short* h1  = (unsigned short*)ws;                  // 25,600,000
  float*          agg = (float*)(ws + 25600000);              // 51,200,000
  char* wbase = ws + 25600000 + 51200000;                     // 76,800,000
  unsigned short* awt = (unsigned short*)wbase;               // 131072
  unsigned short* m2t = awt + 65536;                          // 131072
  unsigned short* o1t = m2t + 65536;                          // 131072
  unsigned short* o2t = o1t + 65536;                          // 131072
  unsigned short* m1t = o2t + 65536;                          // 32768
  char* p0 = wbase + 4 * 131072 + 32768;                      // 77,357,056
  int* cnt    = (int*)p0;                                     // 200,000
  int* cursor = cnt + N_NODES;                                // 200,000
  int* perm   = cursor + N_NODES;                             // 3,200,000
  char* p1 = p0 + 400000 + 3200000;                           // 80,957,056
  float* Cf   = (float*)p1;                                   // 3,200,000
  int*   srcs = (int*)(p1 + 3200000);                         // 3,200,000
  int*   dsts = (int*)(p1 + 6400000);                         // 3,200,000
  // total ~90.6 MB

  hipMemsetAsync(agg, 0, (size_t)N_NODES * 256 * 4, stream);
  hipMemsetAsync(cnt, 0, (size_t)N_NODES * 4, stream);

  prep_weights<<<256, 256, 0, stream>>>(awW, m1W, m2W, o1W, o2W,
                                        awt, m1t, m2t, o1t, o2t);
  hist_dst<<<N_EDGES / 256, 256, 0, stream>>>(eidx, cnt);
  scan_cnt<<<1, 1024, 0, stream>>>(cnt, cursor);
  scatter_perm<<<N_EDGES / 256, 256, 0, stream>>>(eidx, ew, cursor, perm,
                                                  Cf, srcs, dsts);

  // h1 = h @ aw_W + aw_b  (bf16 out) — needed by the fused edge kernel
  gemm512<1, 0, 0><<<(N_NODES + 63) / 64, 512, 0, stream>>>(h, awt, awb, h1, N_NODES);

  // fused edge MLP + CFConv aggregation (sorted order, direct eattr gather)
  edge_fused512<<<N_EDGES / 64, 512, 0, stream>>>(
      ea, perm, Cf, srcs, dsts, m1t, m1b, m2t, m2b, h1, agg);

  // o = ssp(agg @ o1_W + o1_b)   (into h1's buffer)
  gemm512<1, 1, 0><<<(N_NODES + 63) / 64, 512, 0, stream>>>(agg, o1t, o1b, h1, N_NODES);
  // out = o @ o2_W + o2_b
  gemm512<0, 0, 1><<<(N_NODES + 63) / 64, 512, 0, stream>>>(h1, o2t, o2b, d_out, N_NODES);
}